// Round 5
// baseline (191.729 us; speedup 1.0000x reference)
//
#include <hip/hip_runtime.h>

// ---------------------------------------------------------------------------
// AI4Urban one-timestep NS solver on 64x128x256, f32.  Round 5 (= R4 fixed):
//  - predictor+corrector fused (bu/bv/bw recomputed in-register at the 7
//    axis-aligned stencil points; never materialized).  -48MB traffic.
//  - level-0 restriction fused into divresid and pup_resid (2-z-plane blocks,
//    LDS reduce).  Down-chain starts at r1.
//  - coarse up-chain fully fused: B(LDS) -> C+halo(LDS) -> D in one kernel.
//  9 dispatches.
// ---------------------------------------------------------------------------

constexpr int NZ = 64, NY = 128, NX = 256;
constexpr int NTOT = NZ * NY * NX;
constexpr float DT  = 0.01f;
constexpr float RE  = 0.001f;
constexpr float UBC = -1.0f;
constexpr float DIAG = -6.0f;
constexpr float SIXTH = 1.0f / 6.0f;

__device__ __forceinline__ int idx3(int z, int y, int x) {
    return (z * NY + y) * NX + x;
}

union F4 { float4 v; float f[4]; };

__device__ __forceinline__ float4 ld4(const float* __restrict__ f, int z, int y, int x0) {
    return *reinterpret_cast<const float4*>(&f[idx3(z, y, x0)]);
}
__device__ __forceinline__ void st4(float* __restrict__ f, int c, const F4& a) {
    *reinterpret_cast<float4*>(&f[c]) = a.v;
}

__device__ __forceinline__ void zero4(float o[4]) {
    #pragma unroll
    for (int i = 0; i < 4; i++) o[i] = 0.f;
}

__device__ __forceinline__ void row0(const float* __restrict__ f, int z, int y, int x0,
                                     bool ok, float o[4]) {
    if (ok) { F4 a; a.v = ld4(f, z, y, x0);
        #pragma unroll
        for (int i = 0; i < 4; i++) o[i] = a.f[i];
    } else {
        zero4(o);
    }
}
__device__ __forceinline__ void row3s(const float* __restrict__ u, const float* __restrict__ v,
                                      const float* __restrict__ w, const float* __restrict__ sg,
                                      int z, int y, int x0, bool ok,
                                      float uo[4], float vo[4], float wo[4]) {
    if (ok) {
        F4 a, b, c, s;
        a.v = ld4(u, z, y, x0); b.v = ld4(v, z, y, x0);
        c.v = ld4(w, z, y, x0); s.v = ld4(sg, z, y, x0);
        #pragma unroll
        for (int i = 0; i < 4; i++) {
            float iv = 1.f / (1.f + DT * s.f[i]);
            uo[i] = a.f[i] * iv; vo[i] = b.f[i] * iv; wo[i] = c.f[i] * iv;
        }
    } else {
        zero4(uo); zero4(vo); zero4(wo);
    }
}

// 4-wide predictor evaluation at row (z,y), x = 4*tx .. 4*tx+3.  (z,y) valid.
__device__ __forceinline__ void bu_row4(
    const float* __restrict__ u, const float* __restrict__ v, const float* __restrict__ w,
    const float* __restrict__ p, const float* __restrict__ sg,
    int z, int y, int tx, float obu[4], float obv[4], float obw[4]) {
    int x0 = tx << 2, c = idx3(z, y, x0);
    F4 sc; sc.v = ld4(sg, z, y, x0);
    F4 u4, v4, w4; u4.v = ld4(u, z, y, x0); v4.v = ld4(v, z, y, x0); w4.v = ld4(w, z, y, x0);
    float inv[4], uc[4], vc[4], wc[4];
    #pragma unroll
    for (int i = 0; i < 4; i++) {
        inv[i] = 1.f / (1.f + DT * sc.f[i]);
        uc[i] = u4.f[i] * inv[i]; vc[i] = v4.f[i] * inv[i]; wc[i] = w4.f[i] * inv[i];
    }
    float uym[4], vym[4], wym[4], uyp[4], vyp[4], wyp[4];
    float uzm[4], vzm[4], wzm[4], uzp[4], vzp[4], wzp[4];
    row3s(u, v, w, sg, z, y - 1, x0, y > 0,      uym, vym, wym);
    row3s(u, v, w, sg, z, y + 1, x0, y < NY - 1, uyp, vyp, wyp);
    row3s(u, v, w, sg, z - 1, y, x0, z > 0,      uzm, vzm, wzm);
    row3s(u, v, w, sg, z + 1, y, x0, z < NZ - 1, uzp, vzp, wzp);

    float uxmS, vxmS, wxmS, uxpS, vxpS, wxpS;
    if (tx > 0) { float iv = 1.f / (1.f + DT * sg[c - 1]);
        uxmS = u[c - 1] * iv; vxmS = v[c - 1] * iv; wxmS = w[c - 1] * iv; }
    else { uxmS = UBC; vxmS = 0.f; wxmS = 0.f; }
    if (tx < 63) { float iv = 1.f / (1.f + DT * sg[c + 4]);
        uxpS = u[c + 4] * iv; vxpS = v[c + 4] * iv; wxpS = w[c + 4] * iv; }
    else { uxpS = vxpS = wxpS = 0.f; }

    F4 pc, pym, pyp, pzm, pzp;
    pc.v  = ld4(p, z, y, x0);
    pym.v = ld4(p, z, y > 0 ? y - 1 : 0, x0);
    pyp.v = ld4(p, z, y < NY - 1 ? y + 1 : y, x0);
    pzm.v = ld4(p, z > 0 ? z - 1 : 0, y, x0);
    pzp.v = ld4(p, z < NZ - 1 ? z + 1 : z, y, x0);
    float pxmS = tx ? p[c - 1] : pc.f[0];
    float pxpS = (tx < 63) ? p[c + 4] : pc.f[3];

    #pragma unroll
    for (int i = 0; i < 4; i++) {
        float uxm = i ? uc[i - 1] : uxmS, uxp = (i < 3) ? uc[i + 1] : uxpS;
        float vxm = i ? vc[i - 1] : vxmS, vxp = (i < 3) ? vc[i + 1] : vxpS;
        float wxm = i ? wc[i - 1] : wxmS, wxp = (i < 3) ? wc[i + 1] : wxpS;
        float pxm = i ? pc.f[i - 1] : pxmS, pxp = (i < 3) ? pc.f[i + 1] : pxpS;
        float dpx = 0.5f * (pxp - pxm);
        float dpy = 0.5f * (pyp.f[i] - pym.f[i]);
        float dpz = 0.5f * (pzp.f[i] - pzm.f[i]);
        float lap_u = uxm + uxp + uym[i] + uyp[i] + uzm[i] + uzp[i] - 6.f * uc[i];
        float lap_v = vxm + vxp + vym[i] + vyp[i] + vzm[i] + vzp[i] - 6.f * vc[i];
        float lap_w = wxm + wxp + wym[i] + wyp[i] + wzm[i] + wzp[i] - 6.f * wc[i];
        float bun = uc[i] + 0.5f * (RE * lap_u * DT
                    - uc[i] * (0.5f * (uxp - uxm)) * DT
                    - vc[i] * (0.5f * (uyp[i] - uym[i])) * DT
                    - wc[i] * (0.5f * (uzp[i] - uzm[i])) * DT) - dpx * DT;
        float bvn = vc[i] + 0.5f * (RE * lap_v * DT
                    - uc[i] * (0.5f * (vxp - vxm)) * DT
                    - vc[i] * (0.5f * (vyp[i] - vym[i])) * DT
                    - wc[i] * (0.5f * (vzp[i] - vzm[i])) * DT) - dpy * DT;
        float bwn = wc[i] + 0.5f * (RE * lap_w * DT
                    - uc[i] * (0.5f * (wxp - wxm)) * DT
                    - vc[i] * (0.5f * (wyp[i] - wym[i])) * DT
                    - wc[i] * (0.5f * (wzp[i] - wzm[i])) * DT) - dpz * DT;
        obu[i] = bun * inv[i];
        obv[i] = bvn * inv[i];
        obw[i] = bwn * inv[i];
    }
}

// scalar predictor evaluation at a single valid point ((z,y) valid, 0<=x<NX)
__device__ __forceinline__ void bu_point(
    const float* __restrict__ u, const float* __restrict__ v, const float* __restrict__ w,
    const float* __restrict__ p, const float* __restrict__ sg,
    int z, int y, int x, float& rbu, float& rbv, float& rbw) {
    int c = idx3(z, y, x);
    float inv = 1.f / (1.f + DT * sg[c]);
    float uc = u[c] * inv, vc = v[c] * inv, wc = w[c] * inv;
    float uxm, vxm, wxm, uxp, vxp, wxp, uym, vym, wym, uyp, vyp, wyp;
    float uzm, vzm, wzm, uzp, vzp, wzp;
    if (x > 0) { int i = c - 1; float iv = 1.f / (1.f + DT * sg[i]);
        uxm = u[i]*iv; vxm = v[i]*iv; wxm = w[i]*iv; } else { uxm = UBC; vxm = wxm = 0.f; }
    if (x < NX - 1) { int i = c + 1; float iv = 1.f / (1.f + DT * sg[i]);
        uxp = u[i]*iv; vxp = v[i]*iv; wxp = w[i]*iv; } else { uxp = vxp = wxp = 0.f; }
    if (y > 0) { int i = c - NX; float iv = 1.f / (1.f + DT * sg[i]);
        uym = u[i]*iv; vym = v[i]*iv; wym = w[i]*iv; } else { uym = vym = wym = 0.f; }
    if (y < NY - 1) { int i = c + NX; float iv = 1.f / (1.f + DT * sg[i]);
        uyp = u[i]*iv; vyp = v[i]*iv; wyp = w[i]*iv; } else { uyp = vyp = wyp = 0.f; }
    if (z > 0) { int i = c - NX*NY; float iv = 1.f / (1.f + DT * sg[i]);
        uzm = u[i]*iv; vzm = v[i]*iv; wzm = w[i]*iv; } else { uzm = vzm = wzm = 0.f; }
    if (z < NZ - 1) { int i = c + NX*NY; float iv = 1.f / (1.f + DT * sg[i]);
        uzp = u[i]*iv; vzp = v[i]*iv; wzp = w[i]*iv; } else { uzp = vzp = wzp = 0.f; }
    float pxm = x > 0 ? p[c - 1] : p[c];
    float pxp = x < NX - 1 ? p[c + 1] : p[c];
    float pym = y > 0 ? p[c - NX] : p[c];
    float pyp = y < NY - 1 ? p[c + NX] : p[c];
    float pzm = z > 0 ? p[c - NX*NY] : p[c];
    float pzp = z < NZ - 1 ? p[c + NX*NY] : p[c];
    float dpx = 0.5f * (pxp - pxm), dpy = 0.5f * (pyp - pym), dpz = 0.5f * (pzp - pzm);
    float lap_u = uxm + uxp + uym + uyp + uzm + uzp - 6.f * uc;
    float lap_v = vxm + vxp + vym + vyp + vzm + vzp - 6.f * vc;
    float lap_w = wxm + wxp + wym + wyp + wzm + wzp - 6.f * wc;
    rbu = (uc + 0.5f * (RE * lap_u * DT - uc * (0.5f * (uxp - uxm)) * DT
          - vc * (0.5f * (uyp - uym)) * DT - wc * (0.5f * (uzp - uzm)) * DT) - dpx * DT) * inv;
    rbv = (vc + 0.5f * (RE * lap_v * DT - uc * (0.5f * (vxp - vxm)) * DT
          - vc * (0.5f * (vyp - vym)) * DT - wc * (0.5f * (vzp - vzm)) * DT) - dpy * DT) * inv;
    rbw = (wc + 0.5f * (RE * lap_w * DT - uc * (0.5f * (wxp - wxm)) * DT
          - vc * (0.5f * (wyp - wym)) * DT - wc * (0.5f * (wzp - wzm)) * DT) - dpz * DT) * inv;
}

// K1: fused momentum predictor+corrector -> u2,v2,w2 (bu/bv/bw never stored)
__global__ __launch_bounds__(256) void k_mom(
    const float* __restrict__ u, const float* __restrict__ v, const float* __restrict__ w,
    const float* __restrict__ sg, const float* __restrict__ p,
    float* __restrict__ u2, float* __restrict__ v2, float* __restrict__ w2) {
    int tx = threadIdx.x, y = blockIdx.x * 4 + threadIdx.y, z = blockIdx.y;
    int x0 = tx << 2, c = idx3(z, y, x0);

    // bu/bv/bw at center row and the 4 y/z neighbor rows
    float buc[4], bvc[4], bwc[4];
    float uym[4], vym[4], wym[4], uyp[4], vyp[4], wyp[4];
    float uzm[4], vzm[4], wzm[4], uzp[4], vzp[4], wzp[4];
    bu_row4(u, v, w, p, sg, z, y, tx, buc, bvc, bwc);
    if (y > 0)      bu_row4(u, v, w, p, sg, z, y - 1, tx, uym, vym, wym);
    else { zero4(uym); zero4(vym); zero4(wym); }
    if (y < NY - 1) bu_row4(u, v, w, p, sg, z, y + 1, tx, uyp, vyp, wyp);
    else { zero4(uyp); zero4(vyp); zero4(wyp); }
    if (z > 0)      bu_row4(u, v, w, p, sg, z - 1, y, tx, uzm, vzm, wzm);
    else { zero4(uzm); zero4(vzm); zero4(wzm); }
    if (z < NZ - 1) bu_row4(u, v, w, p, sg, z + 1, y, tx, uzp, vzp, wzp);
    else { zero4(uzp); zero4(vzp); zero4(wzp); }

    // x-halo scalars of the center row
    float uxmS, vxmS, wxmS, uxpS, vxpS, wxpS;
    if (tx > 0) bu_point(u, v, w, p, sg, z, y, x0 - 1, uxmS, vxmS, wxmS);
    else { uxmS = UBC; vxmS = 0.f; wxmS = 0.f; }
    if (tx < 63) bu_point(u, v, w, p, sg, z, y, x0 + 4, uxpS, vxpS, wxpS);
    else { uxpS = vxpS = wxpS = 0.f; }

    // corrector
    F4 sc; sc.v = ld4(sg, z, y, x0);
    F4 u4, v4, w4; u4.v = ld4(u, z, y, x0); v4.v = ld4(v, z, y, x0); w4.v = ld4(w, z, y, x0);
    F4 pc, pym, pyp, pzm, pzp;
    pc.v  = ld4(p, z, y, x0);
    pym.v = ld4(p, z, y > 0 ? y - 1 : 0, x0);
    pyp.v = ld4(p, z, y < NY - 1 ? y + 1 : y, x0);
    pzm.v = ld4(p, z > 0 ? z - 1 : 0, y, x0);
    pzp.v = ld4(p, z < NZ - 1 ? z + 1 : z, y, x0);
    float pxmS = tx ? p[c - 1] : pc.f[0];
    float pxpS = (tx < 63) ? p[c + 4] : pc.f[3];

    F4 ou, ov, ow;
    #pragma unroll
    for (int i = 0; i < 4; i++) {
        float inv = 1.f / (1.f + DT * sc.f[i]);
        float u1c = u4.f[i] * inv, v1c = v4.f[i] * inv, w1c = w4.f[i] * inv;
        float uxm = i ? buc[i - 1] : uxmS, uxp = (i < 3) ? buc[i + 1] : uxpS;
        float vxm = i ? bvc[i - 1] : vxmS, vxp = (i < 3) ? bvc[i + 1] : vxpS;
        float wxm = i ? bwc[i - 1] : wxmS, wxp = (i < 3) ? bwc[i + 1] : wxpS;
        float pxm = i ? pc.f[i - 1] : pxmS, pxp = (i < 3) ? pc.f[i + 1] : pxpS;
        float dpx = 0.5f * (pxp - pxm);
        float dpy = 0.5f * (pyp.f[i] - pym.f[i]);
        float dpz = 0.5f * (pzp.f[i] - pzm.f[i]);
        float lap_u = uxm + uxp + uym[i] + uyp[i] + uzm[i] + uzp[i] - 6.f * buc[i];
        float lap_v = vxm + vxp + vym[i] + vyp[i] + vzm[i] + vzp[i] - 6.f * bvc[i];
        float lap_w = wxm + wxp + wym[i] + wyp[i] + wzm[i] + wzp[i] - 6.f * bwc[i];
        float un = u1c + RE * lap_u * DT
                   - buc[i] * (0.5f * (uxp - uxm)) * DT
                   - bvc[i] * (0.5f * (uyp[i] - uym[i])) * DT
                   - bwc[i] * (0.5f * (uzp[i] - uzm[i])) * DT - dpx * DT;
        float vn = v1c + RE * lap_v * DT
                   - buc[i] * (0.5f * (vxp - vxm)) * DT
                   - bvc[i] * (0.5f * (vyp[i] - vym[i])) * DT
                   - bwc[i] * (0.5f * (vzp[i] - vzm[i])) * DT - dpy * DT;
        float wn = w1c + RE * lap_w * DT
                   - buc[i] * (0.5f * (wxp - wxm)) * DT
                   - bvc[i] * (0.5f * (wyp[i] - wym[i])) * DT
                   - bwc[i] * (0.5f * (wzp[i] - wzm[i])) * DT - dpz * DT;
        ou.f[i] = un * inv; ov.f[i] = vn * inv; ow.f[i] = wn * inv;
    }
    st4(u2, c, ou); st4(v2, c, ov); st4(w2, c, ow);
}

// K2: r0 = lap_ep(p) - b (b inline), plus fused level-0->1 restriction of r0.
// block (64,4,2), grid (NY/4, NZ/2)
__global__ __launch_bounds__(512) void k_divresid_r(
    const float* __restrict__ u2, const float* __restrict__ v2, const float* __restrict__ w2,
    const float* __restrict__ p, float* __restrict__ r0, float* __restrict__ r1) {
    __shared__ float lds[2][4][256];
    int tx = threadIdx.x, ty = threadIdx.y, tz = threadIdx.z;
    int y = blockIdx.x * 4 + ty, z = blockIdx.y * 2 + tz;
    int x0 = tx << 2, c = idx3(z, y, x0);

    F4 uc; uc.v = ld4(u2, z, y, x0);
    float uxmS = tx ? u2[c - 1] : UBC, uxpS = (tx < 63) ? u2[c + 4] : 0.f;
    float vym[4], vyp[4], wzm[4], wzp[4];
    row0(v2, z, y - 1, x0, y > 0, vym);
    row0(v2, z, y + 1, x0, y < NY - 1, vyp);
    row0(w2, z - 1, y, x0, z > 0, wzm);
    row0(w2, z + 1, y, x0, z < NZ - 1, wzp);

    F4 pc, pym, pyp, pzm, pzp;
    pc.v  = ld4(p, z, y, x0);
    pym.v = ld4(p, z, y > 0 ? y - 1 : 0, x0);
    pyp.v = ld4(p, z, y < NY - 1 ? y + 1 : y, x0);
    pzm.v = ld4(p, z > 0 ? z - 1 : 0, y, x0);
    pzp.v = ld4(p, z < NZ - 1 ? z + 1 : z, y, x0);
    float pxmS = tx ? p[c - 1] : pc.f[0];
    float pxpS = (tx < 63) ? p[c + 4] : pc.f[3];

    F4 o;
    #pragma unroll
    for (int i = 0; i < 4; i++) {
        float uxm = i ? uc.f[i - 1] : uxmS, uxp = (i < 3) ? uc.f[i + 1] : uxpS;
        float bval = -(0.5f * (uxp - uxm) + 0.5f * (vyp[i] - vym[i])
                       + 0.5f * (wzp[i] - wzm[i])) / DT;
        float pxm = i ? pc.f[i - 1] : pxmS, pxp = (i < 3) ? pc.f[i + 1] : pxpS;
        float lap = pxm + pxp + pym.f[i] + pyp.f[i] + pzm.f[i] + pzp.f[i] - 6.f * pc.f[i];
        o.f[i] = lap - bval;
    }
    st4(r0, c, o);
    *reinterpret_cast<float4*>(&lds[tz][ty][x0]) = o.v;
    __syncthreads();
    int tid = (tz * 4 + ty) * 64 + tx;
    if (tid < 256) {
        int y1loc = tid >> 7, x1 = tid & 127;
        int xf = x1 << 1, yf = y1loc << 1;
        float s = lds[0][yf][xf]     + lds[0][yf][xf + 1]
                + lds[0][yf + 1][xf] + lds[0][yf + 1][xf + 1]
                + lds[1][yf][xf]     + lds[1][yf][xf + 1]
                + lds[1][yf + 1][xf] + lds[1][yf + 1][xf + 1];
        int y1 = blockIdx.x * 2 + y1loc, z1 = blockIdx.y;
        r1[(z1 * 64 + y1) * 128 + x1] = 0.125f * s;
    }
}

// K3: coarse down-chain r1(32,64,128) -> r2, r3, r4.  grid(4,4,4), block 512
__global__ __launch_bounds__(512) void k_down(const float* __restrict__ r1,
    float* __restrict__ r2, float* __restrict__ r3, float* __restrict__ r4) {
    __shared__ float l2[4][8][16];
    __shared__ float l3[2][4][8];
    int tid = threadIdx.x;
    int bx = blockIdx.x, by = blockIdx.y, bz = blockIdx.z;
    {
        int tx2 = tid & 15, ty2 = (tid >> 4) & 7, tz2 = tid >> 7;
        int x2 = bx * 16 + tx2, y2 = by * 8 + ty2, z2 = bz * 4 + tz2;
        const float* b0 = &r1[((size_t)(2 * z2) * 64 + 2 * y2) * 128 + 2 * x2];
        float2 a  = *reinterpret_cast<const float2*>(b0);
        float2 bq = *reinterpret_cast<const float2*>(b0 + 128);
        float2 cq = *reinterpret_cast<const float2*>(b0 + 64 * 128);
        float2 dq = *reinterpret_cast<const float2*>(b0 + 64 * 128 + 128);
        float val = 0.125f * (a.x + a.y + bq.x + bq.y + cq.x + cq.y + dq.x + dq.y);
        l2[tz2][ty2][tx2] = val;
        r2[((z2 * 32) + y2) * 64 + x2] = val;
    }
    __syncthreads();
    if (tid < 64) {
        int tx3 = tid & 7, ty3 = (tid >> 3) & 3, tz3 = tid >> 5;
        float s = l2[2*tz3][2*ty3][2*tx3]     + l2[2*tz3][2*ty3][2*tx3+1]
                + l2[2*tz3][2*ty3+1][2*tx3]   + l2[2*tz3][2*ty3+1][2*tx3+1]
                + l2[2*tz3+1][2*ty3][2*tx3]   + l2[2*tz3+1][2*ty3][2*tx3+1]
                + l2[2*tz3+1][2*ty3+1][2*tx3] + l2[2*tz3+1][2*ty3+1][2*tx3+1];
        float val = 0.125f * s;
        l3[tz3][ty3][tx3] = val;
        int x3 = bx * 8 + tx3, y3 = by * 4 + ty3, z3 = bz * 2 + tz3;
        r3[((z3 * 16) + y3) * 32 + x3] = val;
    }
    __syncthreads();
    if (tid < 8) {
        int tx4 = tid & 3, ty4 = tid >> 2;
        float s = l3[0][2*ty4][2*tx4]   + l3[0][2*ty4][2*tx4+1]
                + l3[0][2*ty4+1][2*tx4] + l3[0][2*ty4+1][2*tx4+1]
                + l3[1][2*ty4][2*tx4]   + l3[1][2*ty4][2*tx4+1]
                + l3[1][2*ty4+1][2*tx4] + l3[1][2*ty4+1][2*tx4+1];
        int x4 = bx * 4 + tx4, y4 = by * 2 + ty4, z4 = bz;
        r4[((z4 * 8) + y4) * 16 + x4] = 0.125f * s;
    }
}

__device__ __forceinline__ float a4p(const float* __restrict__ r4, int z3, int y3, int x3) {
    if ((unsigned)z3 >= 8u || (unsigned)y3 >= 16u || (unsigned)x3 >= 32u) return 0.f;
    return r4[(((z3 >> 1) * 8) + (y3 >> 1)) * 16 + (x3 >> 1)] / DIAG;
}

// K4: fused coarse up-chain: A=r4/diag -> B(LDS) -> C+halo(LDS) -> D(level-1 out)
// grid(4,4,4), block 512
__global__ __launch_bounds__(512) void k_upf(const float* __restrict__ r4,
    const float* __restrict__ r3, const float* __restrict__ r2,
    const float* __restrict__ r1, float* __restrict__ D) {
    __shared__ float Bl[4][6][10];   // level-3 tile + halo
    __shared__ float Cl[6][10][18];  // level-2 tile + halo
    int tid = threadIdx.x;
    int bx = blockIdx.x, by = blockIdx.y, bz = blockIdx.z;
    int B0z = bz * 2 - 1, B0y = by * 4 - 1, B0x = bx * 8 - 1;
    if (tid < 240) {
        int lx = tid % 10, ly = (tid / 10) % 6, lz = tid / 60;
        int z3 = B0z + lz, y3 = B0y + ly, x3 = B0x + lx;
        float val = 0.f;
        if ((unsigned)z3 < 8u && (unsigned)y3 < 16u && (unsigned)x3 < 32u) {
            float wcn = r4[(((z3 >> 1) * 8) + (y3 >> 1)) * 16 + (x3 >> 1)] / DIAG;
            float lap = a4p(r4, z3 - 1, y3, x3) + a4p(r4, z3 + 1, y3, x3)
                      + a4p(r4, z3, y3 - 1, x3) + a4p(r4, z3, y3 + 1, x3)
                      + a4p(r4, z3, y3, x3 - 1) + a4p(r4, z3, y3, x3 + 1) - 6.f * wcn;
            val = wcn - lap / DIAG + r3[((z3 * 16) + y3) * 32 + x3] / DIAG;
        }
        Bl[lz][ly][lx] = val;
    }
    __syncthreads();
    int C0z = bz * 4 - 1, C0y = by * 8 - 1, C0x = bx * 16 - 1;
    auto pB = [&](int z2, int y2, int x2) -> float {
        if ((unsigned)z2 >= 16u || (unsigned)y2 >= 32u || (unsigned)x2 >= 64u) return 0.f;
        return Bl[(z2 >> 1) - B0z][(y2 >> 1) - B0y][(x2 >> 1) - B0x];
    };
    for (int i = tid; i < 1080; i += 512) {
        int lx = i % 18, ly = (i / 18) % 10, lz = i / 180;
        int z2 = C0z + lz, y2 = C0y + ly, x2 = C0x + lx;
        float val = 0.f;
        if ((unsigned)z2 < 16u && (unsigned)y2 < 32u && (unsigned)x2 < 64u) {
            float wB = Bl[(z2 >> 1) - B0z][(y2 >> 1) - B0y][(x2 >> 1) - B0x];
            float lap = pB(z2 - 1, y2, x2) + pB(z2 + 1, y2, x2)
                      + pB(z2, y2 - 1, x2) + pB(z2, y2 + 1, x2)
                      + pB(z2, y2, x2 - 1) + pB(z2, y2, x2 + 1) - 6.f * wB;
            val = wB - lap / DIAG + r2[((z2 * 32) + y2) * 64 + x2] / DIAG;
        }
        Cl[lz][ly][lx] = val;
    }
    __syncthreads();
    auto pC = [&](int z1, int y1, int x1) -> float {
        if ((unsigned)z1 >= 32u || (unsigned)y1 >= 64u || (unsigned)x1 >= 128u) return 0.f;
        return Cl[(z1 >> 1) - C0z][(y1 >> 1) - C0y][(x1 >> 1) - C0x];
    };
    for (int i = tid; i < 4096; i += 512) {
        int lx = i & 31, ly = (i >> 5) & 15, lz = i >> 9;
        int z1 = bz * 8 + lz, y1 = by * 16 + ly, x1 = bx * 32 + lx;
        float wC = Cl[(z1 >> 1) - C0z][(y1 >> 1) - C0y][(x1 >> 1) - C0x];
        float lap = pC(z1 - 1, y1, x1) + pC(z1 + 1, y1, x1)
                  + pC(z1, y1 - 1, x1) + pC(z1, y1 + 1, x1)
                  + pC(z1, y1, x1 - 1) + pC(z1, y1, x1 + 1) - 6.f * wC;
        int idx = (z1 * 64 + y1) * 128 + x1;
        D[idx] = wC - lap / DIAG + r1[idx] / DIAG;
    }
}

// K5: iter0 p-update + iter1 residual (linearity) + fused restriction of r1res.
// block (64,4,2), grid (NY/4, NZ/2)
__global__ __launch_bounds__(512) void k_pup_resid_r(
    const float* __restrict__ pin, const float* __restrict__ D0,
    const float* __restrict__ r0, float* __restrict__ p1, float* __restrict__ r1res,
    float* __restrict__ r1) {
    __shared__ float lds[2][4][256];
    int tx = threadIdx.x, ty = threadIdx.y, tz = threadIdx.z;
    int y = blockIdx.x * 4 + ty, z = blockIdx.y * 2 + tz;
    int x0 = tx << 2, c = idx3(z, y, x0);
    int cz = z >> 1, cy = y >> 1, cx0 = tx << 1;

    const float* Drow = &D0[(cz * 64 + cy) * 128];
    float cr[4];
    cr[1] = Drow[cx0]; cr[2] = Drow[cx0 + 1];
    cr[0] = tx ? Drow[cx0 - 1] : cr[1];
    cr[3] = (tx < 63) ? Drow[cx0 + 2] : cr[2];
    int cym = y ? (y - 1) >> 1 : 0, cyp = (y < NY - 1) ? (y + 1) >> 1 : cy;
    int czm = z ? (z - 1) >> 1 : 0, czp = (z < NZ - 1) ? (z + 1) >> 1 : cz;
    float2 dym = *reinterpret_cast<const float2*>(&D0[(cz * 64 + cym) * 128 + cx0]);
    float2 dyp = *reinterpret_cast<const float2*>(&D0[(cz * 64 + cyp) * 128 + cx0]);
    float2 dzm = *reinterpret_cast<const float2*>(&D0[(czm * 64 + cy) * 128 + cx0]);
    float2 dzp = *reinterpret_cast<const float2*>(&D0[(czp * 64 + cy) * 128 + cx0]);

    F4 rc, rym, ryp, rzm, rzp, pin4;
    rc.v  = ld4(r0, z, y, x0);
    rym.v = ld4(r0, z, y > 0 ? y - 1 : 0, x0);
    ryp.v = ld4(r0, z, y < NY - 1 ? y + 1 : y, x0);
    rzm.v = ld4(r0, z > 0 ? z - 1 : 0, y, x0);
    rzp.v = ld4(r0, z < NZ - 1 ? z + 1 : z, y, x0);
    pin4.v = ld4(pin, z, y, x0);
    float rxmS = tx ? r0[c - 1] : rc.f[0];
    float rxpS = (tx < 63) ? r0[c + 4] : rc.f[3];

    F4 op1, ores;
    #pragma unroll
    for (int i = 0; i < 4; i++) {
        float Dc  = cr[1 + (i >> 1)];
        float Dxm = (i == 0) ? cr[0] : cr[1 + ((i - 1) >> 1)];
        float Dxp = (i == 3) ? cr[3] : cr[1 + ((i + 1) >> 1)];
        float Dym = (i < 2) ? dym.x : dym.y;
        float Dyp = (i < 2) ? dyp.x : dyp.y;
        float Dzm = (i < 2) ? dzm.x : dzm.y;
        float Dzp = (i < 2) ? dzp.x : dzp.y;
        float lapD = Dxm + Dxp + Dym + Dyp + Dzm + Dzp - 6.f * Dc;
        float rxm = i ? rc.f[i - 1] : rxmS, rxp = (i < 3) ? rc.f[i + 1] : rxpS;
        float lapR = rxm + rxp + rym.f[i] + ryp.f[i] + rzm.f[i] + rzp.f[i] - 6.f * rc.f[i];
        op1.f[i]  = pin4.f[i] - Dc + rc.f[i] * SIXTH;
        ores.f[i] = rc.f[i] - lapD + lapR * SIXTH;
    }
    st4(p1, c, op1); st4(r1res, c, ores);
    *reinterpret_cast<float4*>(&lds[tz][ty][x0]) = ores.v;
    __syncthreads();
    int tid = (tz * 4 + ty) * 64 + tx;
    if (tid < 256) {
        int y1loc = tid >> 7, x1 = tid & 127;
        int xf = x1 << 1, yf = y1loc << 1;
        float s = lds[0][yf][xf]     + lds[0][yf][xf + 1]
                + lds[0][yf + 1][xf] + lds[0][yf + 1][xf + 1]
                + lds[1][yf][xf]     + lds[1][yf][xf + 1]
                + lds[1][yf + 1][xf] + lds[1][yf + 1][xf + 1];
        int y1 = blockIdx.x * 2 + y1loc, z1 = blockIdx.y;
        r1[(z1 * 64 + y1) * 128 + x1] = 0.125f * s;
    }
}

// K6: final p-update: p2 = p1 - prol(D1) + r1res/6 ; wmg = prol(D1)
__global__ __launch_bounds__(256) void k_pup2(
    const float* __restrict__ D1, const float* __restrict__ r1res,
    float* __restrict__ pIO, float* __restrict__ wmg) {
    int tx = threadIdx.x, y = blockIdx.x * 4 + threadIdx.y, z = blockIdx.y;
    int x0 = tx << 2, c = idx3(z, y, x0);
    int cz = z >> 1, cy = y >> 1, cx0 = tx << 1;
    float2 d2 = *reinterpret_cast<const float2*>(&D1[(cz * 64 + cy) * 128 + cx0]);
    F4 rr, pp; rr.v = ld4(r1res, z, y, x0); pp.v = ld4(pIO, z, y, x0);
    F4 op, ow;
    #pragma unroll
    for (int i = 0; i < 4; i++) {
        float wv = (i < 2) ? d2.x : d2.y;
        op.f[i] = pp.f[i] - wv + rr.f[i] * SIXTH;
        ow.f[i] = wv;
    }
    st4(pIO, c, op); st4(wmg, c, ow);
}

// K7: projection + final solid_body
__global__ __launch_bounds__(256) void k_final(
    const float* __restrict__ p,
    const float* __restrict__ u2, const float* __restrict__ v2, const float* __restrict__ w2,
    const float* __restrict__ sg,
    float* __restrict__ uo, float* __restrict__ vo, float* __restrict__ wo) {
    int tx = threadIdx.x, y = blockIdx.x * 4 + threadIdx.y, z = blockIdx.y;
    int x0 = tx << 2, c = idx3(z, y, x0);
    F4 pc, pym, pyp, pzm, pzp;
    pc.v  = ld4(p, z, y, x0);
    pym.v = ld4(p, z, y > 0 ? y - 1 : 0, x0);
    pyp.v = ld4(p, z, y < NY - 1 ? y + 1 : y, x0);
    pzm.v = ld4(p, z > 0 ? z - 1 : 0, y, x0);
    pzp.v = ld4(p, z < NZ - 1 ? z + 1 : z, y, x0);
    float pxmS = tx ? p[c - 1] : pc.f[0];
    float pxpS = (tx < 63) ? p[c + 4] : pc.f[3];
    F4 sc; sc.v = ld4(sg, z, y, x0);
    F4 a, b, cc; a.v = ld4(u2, z, y, x0); b.v = ld4(v2, z, y, x0); cc.v = ld4(w2, z, y, x0);
    F4 ou, ov, ow;
    #pragma unroll
    for (int i = 0; i < 4; i++) {
        float pxm = i ? pc.f[i - 1] : pxmS, pxp = (i < 3) ? pc.f[i + 1] : pxpS;
        float inv = 1.f / (1.f + DT * sc.f[i]);
        ou.f[i] = (a.f[i]  - 0.5f * (pxp - pxm) * DT) * inv;
        ov.f[i] = (b.f[i]  - 0.5f * (pyp.f[i] - pym.f[i]) * DT) * inv;
        ow.f[i] = (cc.f[i] - 0.5f * (pzp.f[i] - pzm.f[i]) * DT) * inv;
    }
    st4(uo, c, ou); st4(vo, c, ov); st4(wo, c, ow);
}

extern "C" void kernel_launch(void* const* d_in, const int* in_sizes, int n_in,
                              void* d_out, int out_size, void* d_ws, size_t ws_size,
                              hipStream_t stream) {
    const float* in_u  = (const float*)d_in[0];
    const float* in_v  = (const float*)d_in[1];
    const float* in_w  = (const float*)d_in[2];
    const float* in_p  = (const float*)d_in[3];
    const float* in_sg = (const float*)d_in[4];

    float* out   = (float*)d_out;
    float* O_u   = out;                      // r1res -> u_out
    float* O_v   = out + (size_t)NTOT;       // v_out
    float* O_w   = out + (size_t)2 * NTOT;   // w_out
    float* O_p   = out + (size_t)3 * NTOT;   // p1 -> p2
    float* O_wmg = out + (size_t)4 * NTOT;   // r0 -> wmg
    float* O_r   = out + (size_t)5 * NTOT;   // final coarsest residual (512)

    float* ws  = (float*)d_ws;
    float* A0  = ws;                          // u2
    float* A1  = ws + (size_t)NTOT;           // v2
    float* A2  = ws + (size_t)2 * NTOT;       // w2
    float* r1  = ws + (size_t)3 * NTOT;       // 262144
    float* r2  = r1 + 262144;                 // 32768
    float* r3  = r2 + 32768;                  // 4096
    float* r4w = r3 + 4096;                   // 512
    float* Dw  = r4w + 512;                   // 262144

    dim3 gF(NY / 4, NZ);       dim3 bF(64, 4);
    dim3 gF2(NY / 4, NZ / 2);  dim3 bF2(64, 4, 2);
    dim3 gC(4, 4, 4);

    k_mom         <<<gF,  bF,  0, stream>>>(in_u, in_v, in_w, in_sg, in_p, A0, A1, A2);
    k_divresid_r  <<<gF2, bF2, 0, stream>>>(A0, A1, A2, in_p, O_wmg /*r0*/, r1);

    // --- MG iteration 0 ---
    k_down        <<<gC, dim3(512), 0, stream>>>(r1, r2, r3, r4w);
    k_upf         <<<gC, dim3(512), 0, stream>>>(r4w, r3, r2, r1, Dw);
    k_pup_resid_r <<<gF2, bF2, 0, stream>>>(in_p, Dw, O_wmg, O_p /*p1*/, O_u /*r1res*/, r1);

    // --- MG iteration 1 ---
    k_down        <<<gC, dim3(512), 0, stream>>>(r1, r2, r3, O_r);
    k_upf         <<<gC, dim3(512), 0, stream>>>(O_r, r3, r2, r1, Dw);
    k_pup2        <<<gF, bF, 0, stream>>>(Dw, O_u /*r1res*/, O_p /*p1->p2*/, O_wmg /*wmg*/);

    k_final       <<<gF, bF, 0, stream>>>(O_p, A0, A1, A2, in_sg, O_u, O_v, O_w);
}

// Round 6
// 100.307 us; speedup vs baseline: 1.9114x; 1.9114x over previous
//
#include <hip/hip_runtime.h>

// ---------------------------------------------------------------------------
// AI4Urban one-timestep NS solver on 64x128x256, f32.  Round 6:
//  R5 post-mortem: fused predictor+corrector recompute (k_mom) was 147us --
//  latency/VALU-bound, L3 makes stored intermediates nearly free. Reverted to
//  two-pass predict/correct (R3 kernels).  KEPT from R5: restriction fused
//  into divresid/pup_resid, single fused down-chain, fully-fused up-chain.
//  10 dispatches.
// ---------------------------------------------------------------------------

constexpr int NZ = 64, NY = 128, NX = 256;
constexpr int NTOT = NZ * NY * NX;
constexpr float DT  = 0.01f;
constexpr float RE  = 0.001f;
constexpr float UBC = -1.0f;
constexpr float DIAG = -6.0f;
constexpr float SIXTH = 1.0f / 6.0f;

__device__ __forceinline__ int idx3(int z, int y, int x) {
    return (z * NY + y) * NX + x;
}

union F4 { float4 v; float f[4]; };

__device__ __forceinline__ float4 ld4(const float* __restrict__ f, int z, int y, int x0) {
    return *reinterpret_cast<const float4*>(&f[idx3(z, y, x0)]);
}
__device__ __forceinline__ void st4(float* __restrict__ f, int c, const F4& a) {
    *reinterpret_cast<float4*>(&f[c]) = a.v;
}

__device__ __forceinline__ void zero4(float o[4]) {
    #pragma unroll
    for (int i = 0; i < 4; i++) o[i] = 0.f;
}

__device__ __forceinline__ void row0(const float* __restrict__ f, int z, int y, int x0,
                                     bool ok, float o[4]) {
    if (ok) { F4 a; a.v = ld4(f, z, y, x0);
        #pragma unroll
        for (int i = 0; i < 4; i++) o[i] = a.f[i];
    } else {
        zero4(o);
    }
}
__device__ __forceinline__ void row3s(const float* __restrict__ u, const float* __restrict__ v,
                                      const float* __restrict__ w, const float* __restrict__ sg,
                                      int z, int y, int x0, bool ok,
                                      float uo[4], float vo[4], float wo[4]) {
    if (ok) {
        F4 a, b, c, s;
        a.v = ld4(u, z, y, x0); b.v = ld4(v, z, y, x0);
        c.v = ld4(w, z, y, x0); s.v = ld4(sg, z, y, x0);
        #pragma unroll
        for (int i = 0; i < 4; i++) {
            float iv = 1.f / (1.f + DT * s.f[i]);
            uo[i] = a.f[i] * iv; vo[i] = b.f[i] * iv; wo[i] = c.f[i] * iv;
        }
    } else {
        zero4(uo); zero4(vo); zero4(wo);
    }
}

// K1: predictor, solid_body fused (u1 = u/(1+DT*sg) recomputed at stencil pts)
__global__ __launch_bounds__(256) void k_predict(
    const float* __restrict__ u, const float* __restrict__ v, const float* __restrict__ w,
    const float* __restrict__ p, const float* __restrict__ sg,
    float* __restrict__ bu, float* __restrict__ bv, float* __restrict__ bw) {
    int tx = threadIdx.x, y = blockIdx.x * 4 + threadIdx.y, z = blockIdx.y;
    int x0 = tx << 2, c = idx3(z, y, x0);

    F4 sc; sc.v = ld4(sg, z, y, x0);
    F4 u4, v4, w4; u4.v = ld4(u, z, y, x0); v4.v = ld4(v, z, y, x0); w4.v = ld4(w, z, y, x0);
    float inv[4], uc[4], vc[4], wc[4];
    #pragma unroll
    for (int i = 0; i < 4; i++) {
        inv[i] = 1.f / (1.f + DT * sc.f[i]);
        uc[i] = u4.f[i] * inv[i]; vc[i] = v4.f[i] * inv[i]; wc[i] = w4.f[i] * inv[i];
    }
    float uym[4], vym[4], wym[4], uyp[4], vyp[4], wyp[4];
    float uzm[4], vzm[4], wzm[4], uzp[4], vzp[4], wzp[4];
    row3s(u, v, w, sg, z, y - 1, x0, y > 0,      uym, vym, wym);
    row3s(u, v, w, sg, z, y + 1, x0, y < NY - 1, uyp, vyp, wyp);
    row3s(u, v, w, sg, z - 1, y, x0, z > 0,      uzm, vzm, wzm);
    row3s(u, v, w, sg, z + 1, y, x0, z < NZ - 1, uzp, vzp, wzp);

    float uxmS, vxmS, wxmS, uxpS, vxpS, wxpS;
    if (tx > 0) { float iv = 1.f / (1.f + DT * sg[c - 1]);
        uxmS = u[c - 1] * iv; vxmS = v[c - 1] * iv; wxmS = w[c - 1] * iv; }
    else { uxmS = UBC; vxmS = 0.f; wxmS = 0.f; }
    if (tx < 63) { float iv = 1.f / (1.f + DT * sg[c + 4]);
        uxpS = u[c + 4] * iv; vxpS = v[c + 4] * iv; wxpS = w[c + 4] * iv; }
    else { uxpS = vxpS = wxpS = 0.f; }

    F4 pc, pym, pyp, pzm, pzp;
    pc.v  = ld4(p, z, y, x0);
    pym.v = ld4(p, z, y > 0 ? y - 1 : 0, x0);
    pyp.v = ld4(p, z, y < NY - 1 ? y + 1 : y, x0);
    pzm.v = ld4(p, z > 0 ? z - 1 : 0, y, x0);
    pzp.v = ld4(p, z < NZ - 1 ? z + 1 : z, y, x0);
    float pxmS = tx ? p[c - 1] : pc.f[0];
    float pxpS = (tx < 63) ? p[c + 4] : pc.f[3];

    F4 obu, obv, obw;
    #pragma unroll
    for (int i = 0; i < 4; i++) {
        float uxm = i ? uc[i - 1] : uxmS, uxp = (i < 3) ? uc[i + 1] : uxpS;
        float vxm = i ? vc[i - 1] : vxmS, vxp = (i < 3) ? vc[i + 1] : vxpS;
        float wxm = i ? wc[i - 1] : wxmS, wxp = (i < 3) ? wc[i + 1] : wxpS;
        float pxm = i ? pc.f[i - 1] : pxmS, pxp = (i < 3) ? pc.f[i + 1] : pxpS;
        float dpx = 0.5f * (pxp - pxm);
        float dpy = 0.5f * (pyp.f[i] - pym.f[i]);
        float dpz = 0.5f * (pzp.f[i] - pzm.f[i]);
        float lap_u = uxm + uxp + uym[i] + uyp[i] + uzm[i] + uzp[i] - 6.f * uc[i];
        float lap_v = vxm + vxp + vym[i] + vyp[i] + vzm[i] + vzp[i] - 6.f * vc[i];
        float lap_w = wxm + wxp + wym[i] + wyp[i] + wzm[i] + wzp[i] - 6.f * wc[i];
        float bun = uc[i] + 0.5f * (RE * lap_u * DT
                    - uc[i] * (0.5f * (uxp - uxm)) * DT
                    - vc[i] * (0.5f * (uyp[i] - uym[i])) * DT
                    - wc[i] * (0.5f * (uzp[i] - uzm[i])) * DT) - dpx * DT;
        float bvn = vc[i] + 0.5f * (RE * lap_v * DT
                    - uc[i] * (0.5f * (vxp - vxm)) * DT
                    - vc[i] * (0.5f * (vyp[i] - vym[i])) * DT
                    - wc[i] * (0.5f * (vzp[i] - vzm[i])) * DT) - dpy * DT;
        float bwn = wc[i] + 0.5f * (RE * lap_w * DT
                    - uc[i] * (0.5f * (wxp - wxm)) * DT
                    - vc[i] * (0.5f * (wyp[i] - wym[i])) * DT
                    - wc[i] * (0.5f * (wzp[i] - wzm[i])) * DT) - dpz * DT;
        obu.f[i] = bun * inv[i];
        obv.f[i] = bvn * inv[i];
        obw.f[i] = bwn * inv[i];
    }
    st4(bu, c, obu); st4(bv, c, obv); st4(bw, c, obw);
}

// K2: corrector
__global__ __launch_bounds__(256) void k_correct(
    const float* __restrict__ u, const float* __restrict__ v, const float* __restrict__ w,
    const float* __restrict__ sg,
    const float* __restrict__ bu, const float* __restrict__ bv, const float* __restrict__ bw,
    const float* __restrict__ p,
    float* __restrict__ u2, float* __restrict__ v2, float* __restrict__ w2) {
    int tx = threadIdx.x, y = blockIdx.x * 4 + threadIdx.y, z = blockIdx.y;
    int x0 = tx << 2, c = idx3(z, y, x0);

    F4 sc; sc.v = ld4(sg, z, y, x0);
    F4 u4, v4, w4; u4.v = ld4(u, z, y, x0); v4.v = ld4(v, z, y, x0); w4.v = ld4(w, z, y, x0);
    F4 buc, bvc, bwc; buc.v = ld4(bu, z, y, x0); bvc.v = ld4(bv, z, y, x0); bwc.v = ld4(bw, z, y, x0);

    float uym[4], vym[4], wym[4], uyp[4], vyp[4], wyp[4];
    float uzm[4], vzm[4], wzm[4], uzp[4], vzp[4], wzp[4];
    row0(bu, z, y - 1, x0, y > 0, uym);      row0(bv, z, y - 1, x0, y > 0, vym);
    row0(bw, z, y - 1, x0, y > 0, wym);
    row0(bu, z, y + 1, x0, y < NY - 1, uyp); row0(bv, z, y + 1, x0, y < NY - 1, vyp);
    row0(bw, z, y + 1, x0, y < NY - 1, wyp);
    row0(bu, z - 1, y, x0, z > 0, uzm);      row0(bv, z - 1, y, x0, z > 0, vzm);
    row0(bw, z - 1, y, x0, z > 0, wzm);
    row0(bu, z + 1, y, x0, z < NZ - 1, uzp); row0(bv, z + 1, y, x0, z < NZ - 1, vzp);
    row0(bw, z + 1, y, x0, z < NZ - 1, wzp);

    float uxmS = tx ? bu[c - 1] : UBC,  uxpS = (tx < 63) ? bu[c + 4] : 0.f;
    float vxmS = tx ? bv[c - 1] : 0.f,  vxpS = (tx < 63) ? bv[c + 4] : 0.f;
    float wxmS = tx ? bw[c - 1] : 0.f,  wxpS = (tx < 63) ? bw[c + 4] : 0.f;

    F4 pc, pym, pyp, pzm, pzp;
    pc.v  = ld4(p, z, y, x0);
    pym.v = ld4(p, z, y > 0 ? y - 1 : 0, x0);
    pyp.v = ld4(p, z, y < NY - 1 ? y + 1 : y, x0);
    pzm.v = ld4(p, z > 0 ? z - 1 : 0, y, x0);
    pzp.v = ld4(p, z < NZ - 1 ? z + 1 : z, y, x0);
    float pxmS = tx ? p[c - 1] : pc.f[0];
    float pxpS = (tx < 63) ? p[c + 4] : pc.f[3];

    F4 ou, ov, ow;
    #pragma unroll
    for (int i = 0; i < 4; i++) {
        float inv = 1.f / (1.f + DT * sc.f[i]);
        float u1c = u4.f[i] * inv, v1c = v4.f[i] * inv, w1c = w4.f[i] * inv;
        float uxm = i ? buc.f[i - 1] : uxmS, uxp = (i < 3) ? buc.f[i + 1] : uxpS;
        float vxm = i ? bvc.f[i - 1] : vxmS, vxp = (i < 3) ? bvc.f[i + 1] : vxpS;
        float wxm = i ? bwc.f[i - 1] : wxmS, wxp = (i < 3) ? bwc.f[i + 1] : wxpS;
        float pxm = i ? pc.f[i - 1] : pxmS, pxp = (i < 3) ? pc.f[i + 1] : pxpS;
        float dpx = 0.5f * (pxp - pxm);
        float dpy = 0.5f * (pyp.f[i] - pym.f[i]);
        float dpz = 0.5f * (pzp.f[i] - pzm.f[i]);
        float lap_u = uxm + uxp + uym[i] + uyp[i] + uzm[i] + uzp[i] - 6.f * buc.f[i];
        float lap_v = vxm + vxp + vym[i] + vyp[i] + vzm[i] + vzp[i] - 6.f * bvc.f[i];
        float lap_w = wxm + wxp + wym[i] + wyp[i] + wzm[i] + wzp[i] - 6.f * bwc.f[i];
        float un = u1c + RE * lap_u * DT
                   - buc.f[i] * (0.5f * (uxp - uxm)) * DT
                   - bvc.f[i] * (0.5f * (uyp[i] - uym[i])) * DT
                   - bwc.f[i] * (0.5f * (uzp[i] - uzm[i])) * DT - dpx * DT;
        float vn = v1c + RE * lap_v * DT
                   - buc.f[i] * (0.5f * (vxp - vxm)) * DT
                   - bvc.f[i] * (0.5f * (vyp[i] - vym[i])) * DT
                   - bwc.f[i] * (0.5f * (vzp[i] - vzm[i])) * DT - dpy * DT;
        float wn = w1c + RE * lap_w * DT
                   - buc.f[i] * (0.5f * (wxp - wxm)) * DT
                   - bvc.f[i] * (0.5f * (wyp[i] - wym[i])) * DT
                   - bwc.f[i] * (0.5f * (wzp[i] - wzm[i])) * DT - dpz * DT;
        ou.f[i] = un * inv; ov.f[i] = vn * inv; ow.f[i] = wn * inv;
    }
    st4(u2, c, ou); st4(v2, c, ov); st4(w2, c, ow);
}

// K3: r0 = lap_ep(p) - b (b inline), plus fused level-0->1 restriction of r0.
// block (64,4,2), grid (NY/4, NZ/2)
__global__ __launch_bounds__(512) void k_divresid_r(
    const float* __restrict__ u2, const float* __restrict__ v2, const float* __restrict__ w2,
    const float* __restrict__ p, float* __restrict__ r0, float* __restrict__ r1) {
    __shared__ float lds[2][4][256];
    int tx = threadIdx.x, ty = threadIdx.y, tz = threadIdx.z;
    int y = blockIdx.x * 4 + ty, z = blockIdx.y * 2 + tz;
    int x0 = tx << 2, c = idx3(z, y, x0);

    F4 uc; uc.v = ld4(u2, z, y, x0);
    float uxmS = tx ? u2[c - 1] : UBC, uxpS = (tx < 63) ? u2[c + 4] : 0.f;
    float vym[4], vyp[4], wzm[4], wzp[4];
    row0(v2, z, y - 1, x0, y > 0, vym);
    row0(v2, z, y + 1, x0, y < NY - 1, vyp);
    row0(w2, z - 1, y, x0, z > 0, wzm);
    row0(w2, z + 1, y, x0, z < NZ - 1, wzp);

    F4 pc, pym, pyp, pzm, pzp;
    pc.v  = ld4(p, z, y, x0);
    pym.v = ld4(p, z, y > 0 ? y - 1 : 0, x0);
    pyp.v = ld4(p, z, y < NY - 1 ? y + 1 : y, x0);
    pzm.v = ld4(p, z > 0 ? z - 1 : 0, y, x0);
    pzp.v = ld4(p, z < NZ - 1 ? z + 1 : z, y, x0);
    float pxmS = tx ? p[c - 1] : pc.f[0];
    float pxpS = (tx < 63) ? p[c + 4] : pc.f[3];

    F4 o;
    #pragma unroll
    for (int i = 0; i < 4; i++) {
        float uxm = i ? uc.f[i - 1] : uxmS, uxp = (i < 3) ? uc.f[i + 1] : uxpS;
        float bval = -(0.5f * (uxp - uxm) + 0.5f * (vyp[i] - vym[i])
                       + 0.5f * (wzp[i] - wzm[i])) / DT;
        float pxm = i ? pc.f[i - 1] : pxmS, pxp = (i < 3) ? pc.f[i + 1] : pxpS;
        float lap = pxm + pxp + pym.f[i] + pyp.f[i] + pzm.f[i] + pzp.f[i] - 6.f * pc.f[i];
        o.f[i] = lap - bval;
    }
    st4(r0, c, o);
    *reinterpret_cast<float4*>(&lds[tz][ty][x0]) = o.v;
    __syncthreads();
    int tid = (tz * 4 + ty) * 64 + tx;
    if (tid < 256) {
        int y1loc = tid >> 7, x1 = tid & 127;
        int xf = x1 << 1, yf = y1loc << 1;
        float s = lds[0][yf][xf]     + lds[0][yf][xf + 1]
                + lds[0][yf + 1][xf] + lds[0][yf + 1][xf + 1]
                + lds[1][yf][xf]     + lds[1][yf][xf + 1]
                + lds[1][yf + 1][xf] + lds[1][yf + 1][xf + 1];
        int y1 = blockIdx.x * 2 + y1loc, z1 = blockIdx.y;
        r1[(z1 * 64 + y1) * 128 + x1] = 0.125f * s;
    }
}

// K4: coarse down-chain r1(32,64,128) -> r2, r3, r4.  grid(4,4,4), block 512
__global__ __launch_bounds__(512) void k_down(const float* __restrict__ r1,
    float* __restrict__ r2, float* __restrict__ r3, float* __restrict__ r4) {
    __shared__ float l2[4][8][16];
    __shared__ float l3[2][4][8];
    int tid = threadIdx.x;
    int bx = blockIdx.x, by = blockIdx.y, bz = blockIdx.z;
    {
        int tx2 = tid & 15, ty2 = (tid >> 4) & 7, tz2 = tid >> 7;
        int x2 = bx * 16 + tx2, y2 = by * 8 + ty2, z2 = bz * 4 + tz2;
        const float* b0 = &r1[((size_t)(2 * z2) * 64 + 2 * y2) * 128 + 2 * x2];
        float2 a  = *reinterpret_cast<const float2*>(b0);
        float2 bq = *reinterpret_cast<const float2*>(b0 + 128);
        float2 cq = *reinterpret_cast<const float2*>(b0 + 64 * 128);
        float2 dq = *reinterpret_cast<const float2*>(b0 + 64 * 128 + 128);
        float val = 0.125f * (a.x + a.y + bq.x + bq.y + cq.x + cq.y + dq.x + dq.y);
        l2[tz2][ty2][tx2] = val;
        r2[((z2 * 32) + y2) * 64 + x2] = val;
    }
    __syncthreads();
    if (tid < 64) {
        int tx3 = tid & 7, ty3 = (tid >> 3) & 3, tz3 = tid >> 5;
        float s = l2[2*tz3][2*ty3][2*tx3]     + l2[2*tz3][2*ty3][2*tx3+1]
                + l2[2*tz3][2*ty3+1][2*tx3]   + l2[2*tz3][2*ty3+1][2*tx3+1]
                + l2[2*tz3+1][2*ty3][2*tx3]   + l2[2*tz3+1][2*ty3][2*tx3+1]
                + l2[2*tz3+1][2*ty3+1][2*tx3] + l2[2*tz3+1][2*ty3+1][2*tx3+1];
        float val = 0.125f * s;
        l3[tz3][ty3][tx3] = val;
        int x3 = bx * 8 + tx3, y3 = by * 4 + ty3, z3 = bz * 2 + tz3;
        r3[((z3 * 16) + y3) * 32 + x3] = val;
    }
    __syncthreads();
    if (tid < 8) {
        int tx4 = tid & 3, ty4 = tid >> 2;
        float s = l3[0][2*ty4][2*tx4]   + l3[0][2*ty4][2*tx4+1]
                + l3[0][2*ty4+1][2*tx4] + l3[0][2*ty4+1][2*tx4+1]
                + l3[1][2*ty4][2*tx4]   + l3[1][2*ty4][2*tx4+1]
                + l3[1][2*ty4+1][2*tx4] + l3[1][2*ty4+1][2*tx4+1];
        int x4 = bx * 4 + tx4, y4 = by * 2 + ty4, z4 = bz;
        r4[((z4 * 8) + y4) * 16 + x4] = 0.125f * s;
    }
}

__device__ __forceinline__ float a4p(const float* __restrict__ r4, int z3, int y3, int x3) {
    if ((unsigned)z3 >= 8u || (unsigned)y3 >= 16u || (unsigned)x3 >= 32u) return 0.f;
    return r4[(((z3 >> 1) * 8) + (y3 >> 1)) * 16 + (x3 >> 1)] / DIAG;
}

// K5: fused coarse up-chain: A=r4/diag -> B(LDS) -> C+halo(LDS) -> D(level-1 out)
// grid(4,4,4), block 512
__global__ __launch_bounds__(512) void k_upf(const float* __restrict__ r4,
    const float* __restrict__ r3, const float* __restrict__ r2,
    const float* __restrict__ r1, float* __restrict__ D) {
    __shared__ float Bl[4][6][10];   // level-3 tile + halo
    __shared__ float Cl[6][10][18];  // level-2 tile + halo
    int tid = threadIdx.x;
    int bx = blockIdx.x, by = blockIdx.y, bz = blockIdx.z;
    int B0z = bz * 2 - 1, B0y = by * 4 - 1, B0x = bx * 8 - 1;
    if (tid < 240) {
        int lx = tid % 10, ly = (tid / 10) % 6, lz = tid / 60;
        int z3 = B0z + lz, y3 = B0y + ly, x3 = B0x + lx;
        float val = 0.f;
        if ((unsigned)z3 < 8u && (unsigned)y3 < 16u && (unsigned)x3 < 32u) {
            float wcn = r4[(((z3 >> 1) * 8) + (y3 >> 1)) * 16 + (x3 >> 1)] / DIAG;
            float lap = a4p(r4, z3 - 1, y3, x3) + a4p(r4, z3 + 1, y3, x3)
                      + a4p(r4, z3, y3 - 1, x3) + a4p(r4, z3, y3 + 1, x3)
                      + a4p(r4, z3, y3, x3 - 1) + a4p(r4, z3, y3, x3 + 1) - 6.f * wcn;
            val = wcn - lap / DIAG + r3[((z3 * 16) + y3) * 32 + x3] / DIAG;
        }
        Bl[lz][ly][lx] = val;
    }
    __syncthreads();
    int C0z = bz * 4 - 1, C0y = by * 8 - 1, C0x = bx * 16 - 1;
    auto pB = [&](int z2, int y2, int x2) -> float {
        if ((unsigned)z2 >= 16u || (unsigned)y2 >= 32u || (unsigned)x2 >= 64u) return 0.f;
        return Bl[(z2 >> 1) - B0z][(y2 >> 1) - B0y][(x2 >> 1) - B0x];
    };
    for (int i = tid; i < 1080; i += 512) {
        int lx = i % 18, ly = (i / 18) % 10, lz = i / 180;
        int z2 = C0z + lz, y2 = C0y + ly, x2 = C0x + lx;
        float val = 0.f;
        if ((unsigned)z2 < 16u && (unsigned)y2 < 32u && (unsigned)x2 < 64u) {
            float wB = Bl[(z2 >> 1) - B0z][(y2 >> 1) - B0y][(x2 >> 1) - B0x];
            float lap = pB(z2 - 1, y2, x2) + pB(z2 + 1, y2, x2)
                      + pB(z2, y2 - 1, x2) + pB(z2, y2 + 1, x2)
                      + pB(z2, y2, x2 - 1) + pB(z2, y2, x2 + 1) - 6.f * wB;
            val = wB - lap / DIAG + r2[((z2 * 32) + y2) * 64 + x2] / DIAG;
        }
        Cl[lz][ly][lx] = val;
    }
    __syncthreads();
    auto pC = [&](int z1, int y1, int x1) -> float {
        if ((unsigned)z1 >= 32u || (unsigned)y1 >= 64u || (unsigned)x1 >= 128u) return 0.f;
        return Cl[(z1 >> 1) - C0z][(y1 >> 1) - C0y][(x1 >> 1) - C0x];
    };
    for (int i = tid; i < 4096; i += 512) {
        int lx = i & 31, ly = (i >> 5) & 15, lz = i >> 9;
        int z1 = bz * 8 + lz, y1 = by * 16 + ly, x1 = bx * 32 + lx;
        float wC = Cl[(z1 >> 1) - C0z][(y1 >> 1) - C0y][(x1 >> 1) - C0x];
        float lap = pC(z1 - 1, y1, x1) + pC(z1 + 1, y1, x1)
                  + pC(z1, y1 - 1, x1) + pC(z1, y1 + 1, x1)
                  + pC(z1, y1, x1 - 1) + pC(z1, y1, x1 + 1) - 6.f * wC;
        int idx = (z1 * 64 + y1) * 128 + x1;
        D[idx] = wC - lap / DIAG + r1[idx] / DIAG;
    }
}

// K6: iter0 p-update + iter1 residual (linearity) + fused restriction of r1res.
// block (64,4,2), grid (NY/4, NZ/2)
__global__ __launch_bounds__(512) void k_pup_resid_r(
    const float* __restrict__ pin, const float* __restrict__ D0,
    const float* __restrict__ r0, float* __restrict__ p1, float* __restrict__ r1res,
    float* __restrict__ r1) {
    __shared__ float lds[2][4][256];
    int tx = threadIdx.x, ty = threadIdx.y, tz = threadIdx.z;
    int y = blockIdx.x * 4 + ty, z = blockIdx.y * 2 + tz;
    int x0 = tx << 2, c = idx3(z, y, x0);
    int cz = z >> 1, cy = y >> 1, cx0 = tx << 1;

    const float* Drow = &D0[(cz * 64 + cy) * 128];
    float cr[4];
    cr[1] = Drow[cx0]; cr[2] = Drow[cx0 + 1];
    cr[0] = tx ? Drow[cx0 - 1] : cr[1];
    cr[3] = (tx < 63) ? Drow[cx0 + 2] : cr[2];
    int cym = y ? (y - 1) >> 1 : 0, cyp = (y < NY - 1) ? (y + 1) >> 1 : cy;
    int czm = z ? (z - 1) >> 1 : 0, czp = (z < NZ - 1) ? (z + 1) >> 1 : cz;
    float2 dym = *reinterpret_cast<const float2*>(&D0[(cz * 64 + cym) * 128 + cx0]);
    float2 dyp = *reinterpret_cast<const float2*>(&D0[(cz * 64 + cyp) * 128 + cx0]);
    float2 dzm = *reinterpret_cast<const float2*>(&D0[(czm * 64 + cy) * 128 + cx0]);
    float2 dzp = *reinterpret_cast<const float2*>(&D0[(czp * 64 + cy) * 128 + cx0]);

    F4 rc, rym, ryp, rzm, rzp, pin4;
    rc.v  = ld4(r0, z, y, x0);
    rym.v = ld4(r0, z, y > 0 ? y - 1 : 0, x0);
    ryp.v = ld4(r0, z, y < NY - 1 ? y + 1 : y, x0);
    rzm.v = ld4(r0, z > 0 ? z - 1 : 0, y, x0);
    rzp.v = ld4(r0, z < NZ - 1 ? z + 1 : z, y, x0);
    pin4.v = ld4(pin, z, y, x0);
    float rxmS = tx ? r0[c - 1] : rc.f[0];
    float rxpS = (tx < 63) ? r0[c + 4] : rc.f[3];

    F4 op1, ores;
    #pragma unroll
    for (int i = 0; i < 4; i++) {
        float Dc  = cr[1 + (i >> 1)];
        float Dxm = (i == 0) ? cr[0] : cr[1 + ((i - 1) >> 1)];
        float Dxp = (i == 3) ? cr[3] : cr[1 + ((i + 1) >> 1)];
        float Dym = (i < 2) ? dym.x : dym.y;
        float Dyp = (i < 2) ? dyp.x : dyp.y;
        float Dzm = (i < 2) ? dzm.x : dzm.y;
        float Dzp = (i < 2) ? dzp.x : dzp.y;
        float lapD = Dxm + Dxp + Dym + Dyp + Dzm + Dzp - 6.f * Dc;
        float rxm = i ? rc.f[i - 1] : rxmS, rxp = (i < 3) ? rc.f[i + 1] : rxpS;
        float lapR = rxm + rxp + rym.f[i] + ryp.f[i] + rzm.f[i] + rzp.f[i] - 6.f * rc.f[i];
        op1.f[i]  = pin4.f[i] - Dc + rc.f[i] * SIXTH;
        ores.f[i] = rc.f[i] - lapD + lapR * SIXTH;
    }
    st4(p1, c, op1); st4(r1res, c, ores);
    *reinterpret_cast<float4*>(&lds[tz][ty][x0]) = ores.v;
    __syncthreads();
    int tid = (tz * 4 + ty) * 64 + tx;
    if (tid < 256) {
        int y1loc = tid >> 7, x1 = tid & 127;
        int xf = x1 << 1, yf = y1loc << 1;
        float s = lds[0][yf][xf]     + lds[0][yf][xf + 1]
                + lds[0][yf + 1][xf] + lds[0][yf + 1][xf + 1]
                + lds[1][yf][xf]     + lds[1][yf][xf + 1]
                + lds[1][yf + 1][xf] + lds[1][yf + 1][xf + 1];
        int y1 = blockIdx.x * 2 + y1loc, z1 = blockIdx.y;
        r1[(z1 * 64 + y1) * 128 + x1] = 0.125f * s;
    }
}

// K7: final p-update: p2 = p1 - prol(D1) + r1res/6 ; wmg = prol(D1)
__global__ __launch_bounds__(256) void k_pup2(
    const float* __restrict__ D1, const float* __restrict__ r1res,
    float* __restrict__ pIO, float* __restrict__ wmg) {
    int tx = threadIdx.x, y = blockIdx.x * 4 + threadIdx.y, z = blockIdx.y;
    int x0 = tx << 2, c = idx3(z, y, x0);
    int cz = z >> 1, cy = y >> 1, cx0 = tx << 1;
    float2 d2 = *reinterpret_cast<const float2*>(&D1[(cz * 64 + cy) * 128 + cx0]);
    F4 rr, pp; rr.v = ld4(r1res, z, y, x0); pp.v = ld4(pIO, z, y, x0);
    F4 op, ow;
    #pragma unroll
    for (int i = 0; i < 4; i++) {
        float wv = (i < 2) ? d2.x : d2.y;
        op.f[i] = pp.f[i] - wv + rr.f[i] * SIXTH;
        ow.f[i] = wv;
    }
    st4(pIO, c, op); st4(wmg, c, ow);
}

// K8: projection + final solid_body
__global__ __launch_bounds__(256) void k_final(
    const float* __restrict__ p,
    const float* __restrict__ u2, const float* __restrict__ v2, const float* __restrict__ w2,
    const float* __restrict__ sg,
    float* __restrict__ uo, float* __restrict__ vo, float* __restrict__ wo) {
    int tx = threadIdx.x, y = blockIdx.x * 4 + threadIdx.y, z = blockIdx.y;
    int x0 = tx << 2, c = idx3(z, y, x0);
    F4 pc, pym, pyp, pzm, pzp;
    pc.v  = ld4(p, z, y, x0);
    pym.v = ld4(p, z, y > 0 ? y - 1 : 0, x0);
    pyp.v = ld4(p, z, y < NY - 1 ? y + 1 : y, x0);
    pzm.v = ld4(p, z > 0 ? z - 1 : 0, y, x0);
    pzp.v = ld4(p, z < NZ - 1 ? z + 1 : z, y, x0);
    float pxmS = tx ? p[c - 1] : pc.f[0];
    float pxpS = (tx < 63) ? p[c + 4] : pc.f[3];
    F4 sc; sc.v = ld4(sg, z, y, x0);
    F4 a, b, cc; a.v = ld4(u2, z, y, x0); b.v = ld4(v2, z, y, x0); cc.v = ld4(w2, z, y, x0);
    F4 ou, ov, ow;
    #pragma unroll
    for (int i = 0; i < 4; i++) {
        float pxm = i ? pc.f[i - 1] : pxmS, pxp = (i < 3) ? pc.f[i + 1] : pxpS;
        float inv = 1.f / (1.f + DT * sc.f[i]);
        ou.f[i] = (a.f[i]  - 0.5f * (pxp - pxm) * DT) * inv;
        ov.f[i] = (b.f[i]  - 0.5f * (pyp.f[i] - pym.f[i]) * DT) * inv;
        ow.f[i] = (cc.f[i] - 0.5f * (pzp.f[i] - pzm.f[i]) * DT) * inv;
    }
    st4(uo, c, ou); st4(vo, c, ov); st4(wo, c, ow);
}

extern "C" void kernel_launch(void* const* d_in, const int* in_sizes, int n_in,
                              void* d_out, int out_size, void* d_ws, size_t ws_size,
                              hipStream_t stream) {
    const float* in_u  = (const float*)d_in[0];
    const float* in_v  = (const float*)d_in[1];
    const float* in_w  = (const float*)d_in[2];
    const float* in_p  = (const float*)d_in[3];
    const float* in_sg = (const float*)d_in[4];

    float* out   = (float*)d_out;
    float* O_u   = out;                      // bu -> r1res -> u_out
    float* O_v   = out + (size_t)NTOT;       // bv -> v_out
    float* O_w   = out + (size_t)2 * NTOT;   // bw -> w_out
    float* O_p   = out + (size_t)3 * NTOT;   // p1 -> p2
    float* O_wmg = out + (size_t)4 * NTOT;   // r0 -> wmg
    float* O_r   = out + (size_t)5 * NTOT;   // final coarsest residual (512)

    float* ws  = (float*)d_ws;
    float* A0  = ws;                          // u2
    float* A1  = ws + (size_t)NTOT;           // v2
    float* A2  = ws + (size_t)2 * NTOT;       // w2
    float* r1  = ws + (size_t)3 * NTOT;       // 262144
    float* r2  = r1 + 262144;                 // 32768
    float* r3  = r2 + 32768;                  // 4096
    float* r4w = r3 + 4096;                   // 512
    float* Dw  = r4w + 512;                   // 262144

    dim3 gF(NY / 4, NZ);       dim3 bF(64, 4);
    dim3 gF2(NY / 4, NZ / 2);  dim3 bF2(64, 4, 2);
    dim3 gC(4, 4, 4);

    k_predict     <<<gF,  bF,  0, stream>>>(in_u, in_v, in_w, in_p, in_sg, O_u, O_v, O_w);
    k_correct     <<<gF,  bF,  0, stream>>>(in_u, in_v, in_w, in_sg, O_u, O_v, O_w, in_p, A0, A1, A2);
    k_divresid_r  <<<gF2, bF2, 0, stream>>>(A0, A1, A2, in_p, O_wmg /*r0*/, r1);

    // --- MG iteration 0 ---
    k_down        <<<gC, dim3(512), 0, stream>>>(r1, r2, r3, r4w);
    k_upf         <<<gC, dim3(512), 0, stream>>>(r4w, r3, r2, r1, Dw);
    k_pup_resid_r <<<gF2, bF2, 0, stream>>>(in_p, Dw, O_wmg, O_p /*p1*/, O_u /*r1res*/, r1);

    // --- MG iteration 1 ---
    k_down        <<<gC, dim3(512), 0, stream>>>(r1, r2, r3, O_r);
    k_upf         <<<gC, dim3(512), 0, stream>>>(O_r, r3, r2, r1, Dw);
    k_pup2        <<<gF, bF, 0, stream>>>(Dw, O_u /*r1res*/, O_p /*p1->p2*/, O_wmg /*wmg*/);

    k_final       <<<gF, bF, 0, stream>>>(O_p, A0, A1, A2, in_sg, O_u, O_v, O_w);
}

// Round 7
// 93.439 us; speedup vs baseline: 2.0519x; 1.0735x over previous
//
#include <hip/hip_runtime.h>

// ---------------------------------------------------------------------------
// AI4Urban one-timestep NS solver on 64x128x256, f32.  Round 7:
//  R6 + two changes (structure unchanged, 10 dispatches):
//  - XCD-aware z-slab swizzle on the 5 fine stencil kernels (1D grid; XCD k
//    owns z in [8k,8k+8)) -> y/z neighbor rows hit the local 4MB L2.
//  - All divisions -> fast rcp / reciprocal-const multiplies (tolerance 27x).
// ---------------------------------------------------------------------------

constexpr int NZ = 64, NY = 128, NX = 256;
constexpr int NTOT = NZ * NY * NX;
constexpr float DT  = 0.01f;
constexpr float RDT = 100.0f;          // 1/DT
constexpr float RE  = 0.001f;
constexpr float UBC = -1.0f;
constexpr float SIXTH = 1.0f / 6.0f;
constexpr float IDIAG = -1.0f / 6.0f;  // 1/DIAG, DIAG=-6

__device__ __forceinline__ float frcp(float x) { return __builtin_amdgcn_rcpf(x); }

__device__ __forceinline__ int idx3(int z, int y, int x) {
    return (z * NY + y) * NX + x;
}

union F4 { float4 v; float f[4]; };

__device__ __forceinline__ float4 ld4(const float* __restrict__ f, int z, int y, int x0) {
    return *reinterpret_cast<const float4*>(&f[idx3(z, y, x0)]);
}
__device__ __forceinline__ void st4(float* __restrict__ f, int c, const F4& a) {
    *reinterpret_cast<float4*>(&f[c]) = a.v;
}

__device__ __forceinline__ void zero4(float o[4]) {
    #pragma unroll
    for (int i = 0; i < 4; i++) o[i] = 0.f;
}

__device__ __forceinline__ void row0(const float* __restrict__ f, int z, int y, int x0,
                                     bool ok, float o[4]) {
    if (ok) { F4 a; a.v = ld4(f, z, y, x0);
        #pragma unroll
        for (int i = 0; i < 4; i++) o[i] = a.f[i];
    } else {
        zero4(o);
    }
}
__device__ __forceinline__ void row3s(const float* __restrict__ u, const float* __restrict__ v,
                                      const float* __restrict__ w, const float* __restrict__ sg,
                                      int z, int y, int x0, bool ok,
                                      float uo[4], float vo[4], float wo[4]) {
    if (ok) {
        F4 a, b, c, s;
        a.v = ld4(u, z, y, x0); b.v = ld4(v, z, y, x0);
        c.v = ld4(w, z, y, x0); s.v = ld4(sg, z, y, x0);
        #pragma unroll
        for (int i = 0; i < 4; i++) {
            float iv = frcp(1.f + DT * s.f[i]);
            uo[i] = a.f[i] * iv; vo[i] = b.f[i] * iv; wo[i] = c.f[i] * iv;
        }
    } else {
        zero4(uo); zero4(vo); zero4(wo);
    }
}

// XCD z-slab swizzle decode: 2048 blocks, block (64,4).
// XCD k = d&7 owns z in [8k, 8k+8); within: ytile = j&31, z = 8k + (j>>5).
__device__ __forceinline__ void decode_f(int d, int& y, int& z) {
    int k = d & 7, j = d >> 3;
    z = 8 * k + (j >> 5);
    y = (j & 31) * 4 + threadIdx.y;
}
// 1024 blocks, block (64,4,2): XCD k owns ztile in [4k,4k+4) (z-slab of 8).
__device__ __forceinline__ void decode_f2(int d, int& y, int& z, int& ytile, int& ztile) {
    int k = d & 7, j = d >> 3;
    ztile = 4 * k + (j >> 5);
    ytile = j & 31;
    z = ztile * 2 + threadIdx.z;
    y = ytile * 4 + threadIdx.y;
}

// K1: predictor, solid_body fused
__global__ __launch_bounds__(256) void k_predict(
    const float* __restrict__ u, const float* __restrict__ v, const float* __restrict__ w,
    const float* __restrict__ p, const float* __restrict__ sg,
    float* __restrict__ bu, float* __restrict__ bv, float* __restrict__ bw) {
    int tx = threadIdx.x, y, z;
    decode_f(blockIdx.x, y, z);
    int x0 = tx << 2, c = idx3(z, y, x0);

    F4 sc; sc.v = ld4(sg, z, y, x0);
    F4 u4, v4, w4; u4.v = ld4(u, z, y, x0); v4.v = ld4(v, z, y, x0); w4.v = ld4(w, z, y, x0);
    float inv[4], uc[4], vc[4], wc[4];
    #pragma unroll
    for (int i = 0; i < 4; i++) {
        inv[i] = frcp(1.f + DT * sc.f[i]);
        uc[i] = u4.f[i] * inv[i]; vc[i] = v4.f[i] * inv[i]; wc[i] = w4.f[i] * inv[i];
    }
    float uym[4], vym[4], wym[4], uyp[4], vyp[4], wyp[4];
    float uzm[4], vzm[4], wzm[4], uzp[4], vzp[4], wzp[4];
    row3s(u, v, w, sg, z, y - 1, x0, y > 0,      uym, vym, wym);
    row3s(u, v, w, sg, z, y + 1, x0, y < NY - 1, uyp, vyp, wyp);
    row3s(u, v, w, sg, z - 1, y, x0, z > 0,      uzm, vzm, wzm);
    row3s(u, v, w, sg, z + 1, y, x0, z < NZ - 1, uzp, vzp, wzp);

    float uxmS, vxmS, wxmS, uxpS, vxpS, wxpS;
    if (tx > 0) { float iv = frcp(1.f + DT * sg[c - 1]);
        uxmS = u[c - 1] * iv; vxmS = v[c - 1] * iv; wxmS = w[c - 1] * iv; }
    else { uxmS = UBC; vxmS = 0.f; wxmS = 0.f; }
    if (tx < 63) { float iv = frcp(1.f + DT * sg[c + 4]);
        uxpS = u[c + 4] * iv; vxpS = v[c + 4] * iv; wxpS = w[c + 4] * iv; }
    else { uxpS = vxpS = wxpS = 0.f; }

    F4 pc, pym, pyp, pzm, pzp;
    pc.v  = ld4(p, z, y, x0);
    pym.v = ld4(p, z, y > 0 ? y - 1 : 0, x0);
    pyp.v = ld4(p, z, y < NY - 1 ? y + 1 : y, x0);
    pzm.v = ld4(p, z > 0 ? z - 1 : 0, y, x0);
    pzp.v = ld4(p, z < NZ - 1 ? z + 1 : z, y, x0);
    float pxmS = tx ? p[c - 1] : pc.f[0];
    float pxpS = (tx < 63) ? p[c + 4] : pc.f[3];

    F4 obu, obv, obw;
    #pragma unroll
    for (int i = 0; i < 4; i++) {
        float uxm = i ? uc[i - 1] : uxmS, uxp = (i < 3) ? uc[i + 1] : uxpS;
        float vxm = i ? vc[i - 1] : vxmS, vxp = (i < 3) ? vc[i + 1] : vxpS;
        float wxm = i ? wc[i - 1] : wxmS, wxp = (i < 3) ? wc[i + 1] : wxpS;
        float pxm = i ? pc.f[i - 1] : pxmS, pxp = (i < 3) ? pc.f[i + 1] : pxpS;
        float dpx = 0.5f * (pxp - pxm);
        float dpy = 0.5f * (pyp.f[i] - pym.f[i]);
        float dpz = 0.5f * (pzp.f[i] - pzm.f[i]);
        float lap_u = uxm + uxp + uym[i] + uyp[i] + uzm[i] + uzp[i] - 6.f * uc[i];
        float lap_v = vxm + vxp + vym[i] + vyp[i] + vzm[i] + vzp[i] - 6.f * vc[i];
        float lap_w = wxm + wxp + wym[i] + wyp[i] + wzm[i] + wzp[i] - 6.f * wc[i];
        float bun = uc[i] + 0.5f * (RE * lap_u * DT
                    - uc[i] * (0.5f * (uxp - uxm)) * DT
                    - vc[i] * (0.5f * (uyp[i] - uym[i])) * DT
                    - wc[i] * (0.5f * (uzp[i] - uzm[i])) * DT) - dpx * DT;
        float bvn = vc[i] + 0.5f * (RE * lap_v * DT
                    - uc[i] * (0.5f * (vxp - vxm)) * DT
                    - vc[i] * (0.5f * (vyp[i] - vym[i])) * DT
                    - wc[i] * (0.5f * (vzp[i] - vzm[i])) * DT) - dpy * DT;
        float bwn = wc[i] + 0.5f * (RE * lap_w * DT
                    - uc[i] * (0.5f * (wxp - wxm)) * DT
                    - vc[i] * (0.5f * (wyp[i] - wym[i])) * DT
                    - wc[i] * (0.5f * (wzp[i] - wzm[i])) * DT) - dpz * DT;
        obu.f[i] = bun * inv[i];
        obv.f[i] = bvn * inv[i];
        obw.f[i] = bwn * inv[i];
    }
    st4(bu, c, obu); st4(bv, c, obv); st4(bw, c, obw);
}

// K2: corrector
__global__ __launch_bounds__(256) void k_correct(
    const float* __restrict__ u, const float* __restrict__ v, const float* __restrict__ w,
    const float* __restrict__ sg,
    const float* __restrict__ bu, const float* __restrict__ bv, const float* __restrict__ bw,
    const float* __restrict__ p,
    float* __restrict__ u2, float* __restrict__ v2, float* __restrict__ w2) {
    int tx = threadIdx.x, y, z;
    decode_f(blockIdx.x, y, z);
    int x0 = tx << 2, c = idx3(z, y, x0);

    F4 sc; sc.v = ld4(sg, z, y, x0);
    F4 u4, v4, w4; u4.v = ld4(u, z, y, x0); v4.v = ld4(v, z, y, x0); w4.v = ld4(w, z, y, x0);
    F4 buc, bvc, bwc; buc.v = ld4(bu, z, y, x0); bvc.v = ld4(bv, z, y, x0); bwc.v = ld4(bw, z, y, x0);

    float uym[4], vym[4], wym[4], uyp[4], vyp[4], wyp[4];
    float uzm[4], vzm[4], wzm[4], uzp[4], vzp[4], wzp[4];
    row0(bu, z, y - 1, x0, y > 0, uym);      row0(bv, z, y - 1, x0, y > 0, vym);
    row0(bw, z, y - 1, x0, y > 0, wym);
    row0(bu, z, y + 1, x0, y < NY - 1, uyp); row0(bv, z, y + 1, x0, y < NY - 1, vyp);
    row0(bw, z, y + 1, x0, y < NY - 1, wyp);
    row0(bu, z - 1, y, x0, z > 0, uzm);      row0(bv, z - 1, y, x0, z > 0, vzm);
    row0(bw, z - 1, y, x0, z > 0, wzm);
    row0(bu, z + 1, y, x0, z < NZ - 1, uzp); row0(bv, z + 1, y, x0, z < NZ - 1, vzp);
    row0(bw, z + 1, y, x0, z < NZ - 1, wzp);

    float uxmS = tx ? bu[c - 1] : UBC,  uxpS = (tx < 63) ? bu[c + 4] : 0.f;
    float vxmS = tx ? bv[c - 1] : 0.f,  vxpS = (tx < 63) ? bv[c + 4] : 0.f;
    float wxmS = tx ? bw[c - 1] : 0.f,  wxpS = (tx < 63) ? bw[c + 4] : 0.f;

    F4 pc, pym, pyp, pzm, pzp;
    pc.v  = ld4(p, z, y, x0);
    pym.v = ld4(p, z, y > 0 ? y - 1 : 0, x0);
    pyp.v = ld4(p, z, y < NY - 1 ? y + 1 : y, x0);
    pzm.v = ld4(p, z > 0 ? z - 1 : 0, y, x0);
    pzp.v = ld4(p, z < NZ - 1 ? z + 1 : z, y, x0);
    float pxmS = tx ? p[c - 1] : pc.f[0];
    float pxpS = (tx < 63) ? p[c + 4] : pc.f[3];

    F4 ou, ov, ow;
    #pragma unroll
    for (int i = 0; i < 4; i++) {
        float inv = frcp(1.f + DT * sc.f[i]);
        float u1c = u4.f[i] * inv, v1c = v4.f[i] * inv, w1c = w4.f[i] * inv;
        float uxm = i ? buc.f[i - 1] : uxmS, uxp = (i < 3) ? buc.f[i + 1] : uxpS;
        float vxm = i ? bvc.f[i - 1] : vxmS, vxp = (i < 3) ? bvc.f[i + 1] : vxpS;
        float wxm = i ? bwc.f[i - 1] : wxmS, wxp = (i < 3) ? bwc.f[i + 1] : wxpS;
        float pxm = i ? pc.f[i - 1] : pxmS, pxp = (i < 3) ? pc.f[i + 1] : pxpS;
        float dpx = 0.5f * (pxp - pxm);
        float dpy = 0.5f * (pyp.f[i] - pym.f[i]);
        float dpz = 0.5f * (pzp.f[i] - pzm.f[i]);
        float lap_u = uxm + uxp + uym[i] + uyp[i] + uzm[i] + uzp[i] - 6.f * buc.f[i];
        float lap_v = vxm + vxp + vym[i] + vyp[i] + vzm[i] + vzp[i] - 6.f * bvc.f[i];
        float lap_w = wxm + wxp + wym[i] + wyp[i] + wzm[i] + wzp[i] - 6.f * bwc.f[i];
        float un = u1c + RE * lap_u * DT
                   - buc.f[i] * (0.5f * (uxp - uxm)) * DT
                   - bvc.f[i] * (0.5f * (uyp[i] - uym[i])) * DT
                   - bwc.f[i] * (0.5f * (uzp[i] - uzm[i])) * DT - dpx * DT;
        float vn = v1c + RE * lap_v * DT
                   - buc.f[i] * (0.5f * (vxp - vxm)) * DT
                   - bvc.f[i] * (0.5f * (vyp[i] - vym[i])) * DT
                   - bwc.f[i] * (0.5f * (vzp[i] - vzm[i])) * DT - dpy * DT;
        float wn = w1c + RE * lap_w * DT
                   - buc.f[i] * (0.5f * (wxp - wxm)) * DT
                   - bvc.f[i] * (0.5f * (wyp[i] - wym[i])) * DT
                   - bwc.f[i] * (0.5f * (wzp[i] - wzm[i])) * DT - dpz * DT;
        ou.f[i] = un * inv; ov.f[i] = vn * inv; ow.f[i] = wn * inv;
    }
    st4(u2, c, ou); st4(v2, c, ov); st4(w2, c, ow);
}

// K3: r0 = lap_ep(p) - b (b inline), plus fused level-0->1 restriction of r0.
// 1D grid 1024, block (64,4,2)
__global__ __launch_bounds__(512) void k_divresid_r(
    const float* __restrict__ u2, const float* __restrict__ v2, const float* __restrict__ w2,
    const float* __restrict__ p, float* __restrict__ r0, float* __restrict__ r1) {
    __shared__ float lds[2][4][256];
    int tx = threadIdx.x, ty = threadIdx.y, tz = threadIdx.z;
    int y, z, ytile, ztile;
    decode_f2(blockIdx.x, y, z, ytile, ztile);
    int x0 = tx << 2, c = idx3(z, y, x0);

    F4 uc; uc.v = ld4(u2, z, y, x0);
    float uxmS = tx ? u2[c - 1] : UBC, uxpS = (tx < 63) ? u2[c + 4] : 0.f;
    float vym[4], vyp[4], wzm[4], wzp[4];
    row0(v2, z, y - 1, x0, y > 0, vym);
    row0(v2, z, y + 1, x0, y < NY - 1, vyp);
    row0(w2, z - 1, y, x0, z > 0, wzm);
    row0(w2, z + 1, y, x0, z < NZ - 1, wzp);

    F4 pc, pym, pyp, pzm, pzp;
    pc.v  = ld4(p, z, y, x0);
    pym.v = ld4(p, z, y > 0 ? y - 1 : 0, x0);
    pyp.v = ld4(p, z, y < NY - 1 ? y + 1 : y, x0);
    pzm.v = ld4(p, z > 0 ? z - 1 : 0, y, x0);
    pzp.v = ld4(p, z < NZ - 1 ? z + 1 : z, y, x0);
    float pxmS = tx ? p[c - 1] : pc.f[0];
    float pxpS = (tx < 63) ? p[c + 4] : pc.f[3];

    F4 o;
    #pragma unroll
    for (int i = 0; i < 4; i++) {
        float uxm = i ? uc.f[i - 1] : uxmS, uxp = (i < 3) ? uc.f[i + 1] : uxpS;
        float bval = -(0.5f * (uxp - uxm) + 0.5f * (vyp[i] - vym[i])
                       + 0.5f * (wzp[i] - wzm[i])) * RDT;
        float pxm = i ? pc.f[i - 1] : pxmS, pxp = (i < 3) ? pc.f[i + 1] : pxpS;
        float lap = pxm + pxp + pym.f[i] + pyp.f[i] + pzm.f[i] + pzp.f[i] - 6.f * pc.f[i];
        o.f[i] = lap - bval;
    }
    st4(r0, c, o);
    *reinterpret_cast<float4*>(&lds[tz][ty][x0]) = o.v;
    __syncthreads();
    int tid = (tz * 4 + ty) * 64 + tx;
    if (tid < 256) {
        int y1loc = tid >> 7, x1 = tid & 127;
        int xf = x1 << 1, yf = y1loc << 1;
        float s = lds[0][yf][xf]     + lds[0][yf][xf + 1]
                + lds[0][yf + 1][xf] + lds[0][yf + 1][xf + 1]
                + lds[1][yf][xf]     + lds[1][yf][xf + 1]
                + lds[1][yf + 1][xf] + lds[1][yf + 1][xf + 1];
        int y1 = ytile * 2 + y1loc, z1 = ztile;
        r1[(z1 * 64 + y1) * 128 + x1] = 0.125f * s;
    }
}

// K4: coarse down-chain r1(32,64,128) -> r2, r3, r4.  grid(4,4,4), block 512
__global__ __launch_bounds__(512) void k_down(const float* __restrict__ r1,
    float* __restrict__ r2, float* __restrict__ r3, float* __restrict__ r4) {
    __shared__ float l2[4][8][16];
    __shared__ float l3[2][4][8];
    int tid = threadIdx.x;
    int bx = blockIdx.x, by = blockIdx.y, bz = blockIdx.z;
    {
        int tx2 = tid & 15, ty2 = (tid >> 4) & 7, tz2 = tid >> 7;
        int x2 = bx * 16 + tx2, y2 = by * 8 + ty2, z2 = bz * 4 + tz2;
        const float* b0 = &r1[((size_t)(2 * z2) * 64 + 2 * y2) * 128 + 2 * x2];
        float2 a  = *reinterpret_cast<const float2*>(b0);
        float2 bq = *reinterpret_cast<const float2*>(b0 + 128);
        float2 cq = *reinterpret_cast<const float2*>(b0 + 64 * 128);
        float2 dq = *reinterpret_cast<const float2*>(b0 + 64 * 128 + 128);
        float val = 0.125f * (a.x + a.y + bq.x + bq.y + cq.x + cq.y + dq.x + dq.y);
        l2[tz2][ty2][tx2] = val;
        r2[((z2 * 32) + y2) * 64 + x2] = val;
    }
    __syncthreads();
    if (tid < 64) {
        int tx3 = tid & 7, ty3 = (tid >> 3) & 3, tz3 = tid >> 5;
        float s = l2[2*tz3][2*ty3][2*tx3]     + l2[2*tz3][2*ty3][2*tx3+1]
                + l2[2*tz3][2*ty3+1][2*tx3]   + l2[2*tz3][2*ty3+1][2*tx3+1]
                + l2[2*tz3+1][2*ty3][2*tx3]   + l2[2*tz3+1][2*ty3][2*tx3+1]
                + l2[2*tz3+1][2*ty3+1][2*tx3] + l2[2*tz3+1][2*ty3+1][2*tx3+1];
        float val = 0.125f * s;
        l3[tz3][ty3][tx3] = val;
        int x3 = bx * 8 + tx3, y3 = by * 4 + ty3, z3 = bz * 2 + tz3;
        r3[((z3 * 16) + y3) * 32 + x3] = val;
    }
    __syncthreads();
    if (tid < 8) {
        int tx4 = tid & 3, ty4 = tid >> 2;
        float s = l3[0][2*ty4][2*tx4]   + l3[0][2*ty4][2*tx4+1]
                + l3[0][2*ty4+1][2*tx4] + l3[0][2*ty4+1][2*tx4+1]
                + l3[1][2*ty4][2*tx4]   + l3[1][2*ty4][2*tx4+1]
                + l3[1][2*ty4+1][2*tx4] + l3[1][2*ty4+1][2*tx4+1];
        int x4 = bx * 4 + tx4, y4 = by * 2 + ty4, z4 = bz;
        r4[((z4 * 8) + y4) * 16 + x4] = 0.125f * s;
    }
}

__device__ __forceinline__ float a4p(const float* __restrict__ r4, int z3, int y3, int x3) {
    if ((unsigned)z3 >= 8u || (unsigned)y3 >= 16u || (unsigned)x3 >= 32u) return 0.f;
    return r4[(((z3 >> 1) * 8) + (y3 >> 1)) * 16 + (x3 >> 1)] * IDIAG;
}

// K5: fused coarse up-chain: A=r4/diag -> B(LDS) -> C+halo(LDS) -> D(level-1 out)
__global__ __launch_bounds__(512) void k_upf(const float* __restrict__ r4,
    const float* __restrict__ r3, const float* __restrict__ r2,
    const float* __restrict__ r1, float* __restrict__ D) {
    __shared__ float Bl[4][6][10];
    __shared__ float Cl[6][10][18];
    int tid = threadIdx.x;
    int bx = blockIdx.x, by = blockIdx.y, bz = blockIdx.z;
    int B0z = bz * 2 - 1, B0y = by * 4 - 1, B0x = bx * 8 - 1;
    if (tid < 240) {
        int lx = tid % 10, ly = (tid / 10) % 6, lz = tid / 60;
        int z3 = B0z + lz, y3 = B0y + ly, x3 = B0x + lx;
        float val = 0.f;
        if ((unsigned)z3 < 8u && (unsigned)y3 < 16u && (unsigned)x3 < 32u) {
            float wcn = r4[(((z3 >> 1) * 8) + (y3 >> 1)) * 16 + (x3 >> 1)] * IDIAG;
            float lap = a4p(r4, z3 - 1, y3, x3) + a4p(r4, z3 + 1, y3, x3)
                      + a4p(r4, z3, y3 - 1, x3) + a4p(r4, z3, y3 + 1, x3)
                      + a4p(r4, z3, y3, x3 - 1) + a4p(r4, z3, y3, x3 + 1) - 6.f * wcn;
            val = wcn - lap * IDIAG + r3[((z3 * 16) + y3) * 32 + x3] * IDIAG;
        }
        Bl[lz][ly][lx] = val;
    }
    __syncthreads();
    int C0z = bz * 4 - 1, C0y = by * 8 - 1, C0x = bx * 16 - 1;
    auto pB = [&](int z2, int y2, int x2) -> float {
        if ((unsigned)z2 >= 16u || (unsigned)y2 >= 32u || (unsigned)x2 >= 64u) return 0.f;
        return Bl[(z2 >> 1) - B0z][(y2 >> 1) - B0y][(x2 >> 1) - B0x];
    };
    for (int i = tid; i < 1080; i += 512) {
        int lx = i % 18, ly = (i / 18) % 10, lz = i / 180;
        int z2 = C0z + lz, y2 = C0y + ly, x2 = C0x + lx;
        float val = 0.f;
        if ((unsigned)z2 < 16u && (unsigned)y2 < 32u && (unsigned)x2 < 64u) {
            float wB = Bl[(z2 >> 1) - B0z][(y2 >> 1) - B0y][(x2 >> 1) - B0x];
            float lap = pB(z2 - 1, y2, x2) + pB(z2 + 1, y2, x2)
                      + pB(z2, y2 - 1, x2) + pB(z2, y2 + 1, x2)
                      + pB(z2, y2, x2 - 1) + pB(z2, y2, x2 + 1) - 6.f * wB;
            val = wB - lap * IDIAG + r2[((z2 * 32) + y2) * 64 + x2] * IDIAG;
        }
        Cl[lz][ly][lx] = val;
    }
    __syncthreads();
    auto pC = [&](int z1, int y1, int x1) -> float {
        if ((unsigned)z1 >= 32u || (unsigned)y1 >= 64u || (unsigned)x1 >= 128u) return 0.f;
        return Cl[(z1 >> 1) - C0z][(y1 >> 1) - C0y][(x1 >> 1) - C0x];
    };
    for (int i = tid; i < 4096; i += 512) {
        int lx = i & 31, ly = (i >> 5) & 15, lz = i >> 9;
        int z1 = bz * 8 + lz, y1 = by * 16 + ly, x1 = bx * 32 + lx;
        float wC = Cl[(z1 >> 1) - C0z][(y1 >> 1) - C0y][(x1 >> 1) - C0x];
        float lap = pC(z1 - 1, y1, x1) + pC(z1 + 1, y1, x1)
                  + pC(z1, y1 - 1, x1) + pC(z1, y1 + 1, x1)
                  + pC(z1, y1, x1 - 1) + pC(z1, y1, x1 + 1) - 6.f * wC;
        int idx = (z1 * 64 + y1) * 128 + x1;
        D[idx] = wC - lap * IDIAG + r1[idx] * IDIAG;
    }
}

// K6: iter0 p-update + iter1 residual (linearity) + fused restriction of r1res.
__global__ __launch_bounds__(512) void k_pup_resid_r(
    const float* __restrict__ pin, const float* __restrict__ D0,
    const float* __restrict__ r0, float* __restrict__ p1, float* __restrict__ r1res,
    float* __restrict__ r1) {
    __shared__ float lds[2][4][256];
    int tx = threadIdx.x, ty = threadIdx.y, tz = threadIdx.z;
    int y, z, ytile, ztile;
    decode_f2(blockIdx.x, y, z, ytile, ztile);
    int x0 = tx << 2, c = idx3(z, y, x0);
    int cz = z >> 1, cy = y >> 1, cx0 = tx << 1;

    const float* Drow = &D0[(cz * 64 + cy) * 128];
    float cr[4];
    cr[1] = Drow[cx0]; cr[2] = Drow[cx0 + 1];
    cr[0] = tx ? Drow[cx0 - 1] : cr[1];
    cr[3] = (tx < 63) ? Drow[cx0 + 2] : cr[2];
    int cym = y ? (y - 1) >> 1 : 0, cyp = (y < NY - 1) ? (y + 1) >> 1 : cy;
    int czm = z ? (z - 1) >> 1 : 0, czp = (z < NZ - 1) ? (z + 1) >> 1 : cz;
    float2 dym = *reinterpret_cast<const float2*>(&D0[(cz * 64 + cym) * 128 + cx0]);
    float2 dyp = *reinterpret_cast<const float2*>(&D0[(cz * 64 + cyp) * 128 + cx0]);
    float2 dzm = *reinterpret_cast<const float2*>(&D0[(czm * 64 + cy) * 128 + cx0]);
    float2 dzp = *reinterpret_cast<const float2*>(&D0[(czp * 64 + cy) * 128 + cx0]);

    F4 rc, rym, ryp, rzm, rzp, pin4;
    rc.v  = ld4(r0, z, y, x0);
    rym.v = ld4(r0, z, y > 0 ? y - 1 : 0, x0);
    ryp.v = ld4(r0, z, y < NY - 1 ? y + 1 : y, x0);
    rzm.v = ld4(r0, z > 0 ? z - 1 : 0, y, x0);
    rzp.v = ld4(r0, z < NZ - 1 ? z + 1 : z, y, x0);
    pin4.v = ld4(pin, z, y, x0);
    float rxmS = tx ? r0[c - 1] : rc.f[0];
    float rxpS = (tx < 63) ? r0[c + 4] : rc.f[3];

    F4 op1, ores;
    #pragma unroll
    for (int i = 0; i < 4; i++) {
        float Dc  = cr[1 + (i >> 1)];
        float Dxm = (i == 0) ? cr[0] : cr[1 + ((i - 1) >> 1)];
        float Dxp = (i == 3) ? cr[3] : cr[1 + ((i + 1) >> 1)];
        float Dym = (i < 2) ? dym.x : dym.y;
        float Dyp = (i < 2) ? dyp.x : dyp.y;
        float Dzm = (i < 2) ? dzm.x : dzm.y;
        float Dzp = (i < 2) ? dzp.x : dzp.y;
        float lapD = Dxm + Dxp + Dym + Dyp + Dzm + Dzp - 6.f * Dc;
        float rxm = i ? rc.f[i - 1] : rxmS, rxp = (i < 3) ? rc.f[i + 1] : rxpS;
        float lapR = rxm + rxp + rym.f[i] + ryp.f[i] + rzm.f[i] + rzp.f[i] - 6.f * rc.f[i];
        op1.f[i]  = pin4.f[i] - Dc + rc.f[i] * SIXTH;
        ores.f[i] = rc.f[i] - lapD + lapR * SIXTH;
    }
    st4(p1, c, op1); st4(r1res, c, ores);
    *reinterpret_cast<float4*>(&lds[tz][ty][x0]) = ores.v;
    __syncthreads();
    int tid = (tz * 4 + ty) * 64 + tx;
    if (tid < 256) {
        int y1loc = tid >> 7, x1 = tid & 127;
        int xf = x1 << 1, yf = y1loc << 1;
        float s = lds[0][yf][xf]     + lds[0][yf][xf + 1]
                + lds[0][yf + 1][xf] + lds[0][yf + 1][xf + 1]
                + lds[1][yf][xf]     + lds[1][yf][xf + 1]
                + lds[1][yf + 1][xf] + lds[1][yf + 1][xf + 1];
        int y1 = ytile * 2 + y1loc, z1 = ztile;
        r1[(z1 * 64 + y1) * 128 + x1] = 0.125f * s;
    }
}

// K7: final p-update: p2 = p1 - prol(D1) + r1res/6 ; wmg = prol(D1)
__global__ __launch_bounds__(256) void k_pup2(
    const float* __restrict__ D1, const float* __restrict__ r1res,
    float* __restrict__ pIO, float* __restrict__ wmg) {
    int tx = threadIdx.x, y = blockIdx.x * 4 + threadIdx.y, z = blockIdx.y;
    int x0 = tx << 2, c = idx3(z, y, x0);
    int cz = z >> 1, cy = y >> 1, cx0 = tx << 1;
    float2 d2 = *reinterpret_cast<const float2*>(&D1[(cz * 64 + cy) * 128 + cx0]);
    F4 rr, pp; rr.v = ld4(r1res, z, y, x0); pp.v = ld4(pIO, z, y, x0);
    F4 op, ow;
    #pragma unroll
    for (int i = 0; i < 4; i++) {
        float wv = (i < 2) ? d2.x : d2.y;
        op.f[i] = pp.f[i] - wv + rr.f[i] * SIXTH;
        ow.f[i] = wv;
    }
    st4(pIO, c, op); st4(wmg, c, ow);
}

// K8: projection + final solid_body
__global__ __launch_bounds__(256) void k_final(
    const float* __restrict__ p,
    const float* __restrict__ u2, const float* __restrict__ v2, const float* __restrict__ w2,
    const float* __restrict__ sg,
    float* __restrict__ uo, float* __restrict__ vo, float* __restrict__ wo) {
    int tx = threadIdx.x, y, z;
    decode_f(blockIdx.x, y, z);
    int x0 = tx << 2, c = idx3(z, y, x0);
    F4 pc, pym, pyp, pzm, pzp;
    pc.v  = ld4(p, z, y, x0);
    pym.v = ld4(p, z, y > 0 ? y - 1 : 0, x0);
    pyp.v = ld4(p, z, y < NY - 1 ? y + 1 : y, x0);
    pzm.v = ld4(p, z > 0 ? z - 1 : 0, y, x0);
    pzp.v = ld4(p, z < NZ - 1 ? z + 1 : z, y, x0);
    float pxmS = tx ? p[c - 1] : pc.f[0];
    float pxpS = (tx < 63) ? p[c + 4] : pc.f[3];
    F4 sc; sc.v = ld4(sg, z, y, x0);
    F4 a, b, cc; a.v = ld4(u2, z, y, x0); b.v = ld4(v2, z, y, x0); cc.v = ld4(w2, z, y, x0);
    F4 ou, ov, ow;
    #pragma unroll
    for (int i = 0; i < 4; i++) {
        float pxm = i ? pc.f[i - 1] : pxmS, pxp = (i < 3) ? pc.f[i + 1] : pxpS;
        float inv = frcp(1.f + DT * sc.f[i]);
        ou.f[i] = (a.f[i]  - 0.5f * (pxp - pxm) * DT) * inv;
        ov.f[i] = (b.f[i]  - 0.5f * (pyp.f[i] - pym.f[i]) * DT) * inv;
        ow.f[i] = (cc.f[i] - 0.5f * (pzp.f[i] - pzm.f[i]) * DT) * inv;
    }
    st4(uo, c, ou); st4(vo, c, ov); st4(wo, c, ow);
}

extern "C" void kernel_launch(void* const* d_in, const int* in_sizes, int n_in,
                              void* d_out, int out_size, void* d_ws, size_t ws_size,
                              hipStream_t stream) {
    const float* in_u  = (const float*)d_in[0];
    const float* in_v  = (const float*)d_in[1];
    const float* in_w  = (const float*)d_in[2];
    const float* in_p  = (const float*)d_in[3];
    const float* in_sg = (const float*)d_in[4];

    float* out   = (float*)d_out;
    float* O_u   = out;                      // bu -> r1res -> u_out
    float* O_v   = out + (size_t)NTOT;       // bv -> v_out
    float* O_w   = out + (size_t)2 * NTOT;   // bw -> w_out
    float* O_p   = out + (size_t)3 * NTOT;   // p1 -> p2
    float* O_wmg = out + (size_t)4 * NTOT;   // r0 -> wmg
    float* O_r   = out + (size_t)5 * NTOT;   // final coarsest residual (512)

    float* ws  = (float*)d_ws;
    float* A0  = ws;                          // u2
    float* A1  = ws + (size_t)NTOT;           // v2
    float* A2  = ws + (size_t)2 * NTOT;       // w2
    float* r1  = ws + (size_t)3 * NTOT;       // 262144
    float* r2  = r1 + 262144;                 // 32768
    float* r3  = r2 + 32768;                  // 4096
    float* r4w = r3 + 4096;                   // 512
    float* Dw  = r4w + 512;                   // 262144

    dim3 gF(2048);             dim3 bF(64, 4);
    dim3 gF2(1024);            dim3 bF2(64, 4, 2);
    dim3 gP(NY / 4, NZ);
    dim3 gC(4, 4, 4);

    k_predict     <<<gF,  bF,  0, stream>>>(in_u, in_v, in_w, in_p, in_sg, O_u, O_v, O_w);
    k_correct     <<<gF,  bF,  0, stream>>>(in_u, in_v, in_w, in_sg, O_u, O_v, O_w, in_p, A0, A1, A2);
    k_divresid_r  <<<gF2, bF2, 0, stream>>>(A0, A1, A2, in_p, O_wmg /*r0*/, r1);

    // --- MG iteration 0 ---
    k_down        <<<gC, dim3(512), 0, stream>>>(r1, r2, r3, r4w);
    k_upf         <<<gC, dim3(512), 0, stream>>>(r4w, r3, r2, r1, Dw);
    k_pup_resid_r <<<gF2, bF2, 0, stream>>>(in_p, Dw, O_wmg, O_p /*p1*/, O_u /*r1res*/, r1);

    // --- MG iteration 1 ---
    k_down        <<<gC, dim3(512), 0, stream>>>(r1, r2, r3, O_r);
    k_upf         <<<gC, dim3(512), 0, stream>>>(O_r, r3, r2, r1, Dw);
    k_pup2        <<<gP, bF, 0, stream>>>(Dw, O_u /*r1res*/, O_p /*p1->p2*/, O_wmg /*wmg*/);

    k_final       <<<gF, bF, 0, stream>>>(O_p, A0, A1, A2, in_sg, O_u, O_v, O_w);
}